// Round 15
// baseline (1108.406 us; speedup 1.0000x reference)
//
#include <hip/hip_runtime.h>
#include <cstdint>
#include <cstddef>

// ---------------- types / helpers ----------------
typedef _Float16 f16;
typedef f16 f16x8 __attribute__((ext_vector_type(8)));
typedef float f32x4 __attribute__((ext_vector_type(4)));

#define MFMA(a,b,c) __builtin_amdgcn_mfma_f32_16x16x32_f16(a,b,c,0,0,0)

__device__ __forceinline__ float sigm(float x){ return 1.f/(1.f+__expf(-x)); }
__device__ __forceinline__ float tanh_f(float x){
  float a = __expf(-2.f*fabsf(x));
  float t = (1.f-a)/(1.f+a);
  return x >= 0.f ? t : -t;
}
__device__ __forceinline__ uint16_t f2bf(float f){
  uint32_t u = __float_as_uint(f);
  return (uint16_t)((u + 0x7fffu + ((u>>16)&1u)) >> 16);
}
__device__ __forceinline__ float bf2f(uint16_t h){
  return __uint_as_float(((uint32_t)h) << 16);
}

// ---------------- prep: weights repack (j-major, r9 layout), idx ----------------
// BgT layout [4 groups][256 j][352 k] fp16.
//  k 0..95 = x-part (w_ih cols, valid k<76), k 96..351 = h-part (w_hh cols, kh<252)
//  group 0=r, 1=z, 2=inn (h-part zero), 3=hn (x-part zero). j>=252 -> zero.
__global__ __launch_bounds__(256) void k_prep(
    const float* __restrict__ w_ih, const float* __restrict__ w_hh,
    const float* __restrict__ b_ih, const float* __restrict__ b_hh,
    const int* __restrict__ slen,
    const float* __restrict__ wq, const float* __restrict__ wk,
    const float* __restrict__ gcn_w,
    f16* __restrict__ BgT, f16* __restrict__ wq16, f16* __restrict__ wk16,
    f16* __restrict__ gw16, float* __restrict__ biasc, int* __restrict__ idx)
{
  int id = blockIdx.x*256 + threadIdx.x;
  if (id < 360448){ // BgT: (g*256+j)*352+k
    int g = id / (256*352); int rem = id % (256*352);
    int j = rem / 352; int k = rem % 352;
    float v = 0.f;
    if (j < 252){
      if (k < 96){
        if (k < 76 && g != 3){
          int row = (g==2) ? (504+j) : (g*252+j);
          v = w_ih[row*76 + k];
        }
      } else {
        int kh = k - 96;
        if (kh < 252 && g != 2){
          int row = (g==3) ? (504+j) : (g*252+j);
          v = w_hh[row*252 + kh];
        }
      }
    }
    BgT[id] = (f16)v;
    return;
  }
  id -= 360448;
  if (id < 65536){ wq16[id] = (f16)wq[id]; return; }
  id -= 65536;
  if (id < 65536){ wk16[id] = (f16)wk[id]; return; }
  id -= 65536;
  if (id < 65536){ int j = id >> 8, d = id & 255; gw16[id] = (f16)gcn_w[d*256 + j]; return; }
  id -= 65536;
  if (id < 1008){
    int g = id / 252, j = id % 252; float v;
    if (g==0) v = b_ih[j] + b_hh[j];
    else if (g==1) v = b_ih[252+j] + b_hh[252+j];
    else if (g==2) v = b_ih[504+j];
    else v = b_hh[504+j];
    biasc[id] = v; return;
  }
  id -= 1008;
  if (id < 4096){
    int s = slen[id] - 1; s = s < 0 ? 0 : (s > 47 ? 47 : s);
    idx[id] = s; return;
  }
}

// ---------------- x transpose+convert: x16t[t][n][96] fp16, k>=76 zero ----------------
__global__ __launch_bounds__(256) void k_xt(const float* __restrict__ x,
    f16* __restrict__ x16t)
{
  int id = blockIdx.x*256 + threadIdx.x;   // 48*4096*12 total
  int c = id % 12; int rem = id / 12;
  int n = rem & 4095; int t = rem >> 12;
  const float* xp = x + ((size_t)n*48 + t)*76;
  f16x8 o;
  #pragma unroll
  for (int e = 0; e < 8; ++e){
    int k = c*8 + e;
    o[e] = (k < 76) ? (f16)xp[k] : (f16)0.f;
  }
  *(f16x8*)(x16t + ((size_t)t*4096 + n)*96 + c*8) = o;
}

// ---------------- GRU: persistent, block-local recurrence ----------------
// r14 + three changes driven by the fitted model t = 6.3us + 13.8ns/KB*stream:
//  1. NON-TEMPORAL weight loads for the streamed u>=3 fragments: within a CU
//     the 16 waves read DISJOINT weight slices (zero L1 reuse, 528KB through
//     a 32KB L1 = pure thrash) while x lines ARE reused 16x across waves.
//     nt bypasses/deprioritizes L1 for weights, freeing MSHR/fill for x.
//  2. 8 LDS-cached slots (u0:R/Z/I, u1:R/Z/I, u2:R/Z): stream 416->400KB.
//     hbuf is now SINGLE-buffered (all h reads complete before the epilogue;
//     barrier after reads, barrier after writes) to stay under the 160KB LDS
//     limit with padding headroom (declared 144.1KB).
//  3. idx in registers (idxr), idxl removed.
__global__ __launch_bounds__(1024, 4) void k_gru_all(
    const f16* __restrict__ x16t, const f16* __restrict__ BgT,
    const float* __restrict__ biasc, const float* __restrict__ h0,
    const int* __restrict__ idxp, float* __restrict__ xstar,
    f16* __restrict__ xs16)
{
  __shared__ f16 hbuf[32][256];    // 16 KB (single buffer)
  __shared__ f16 wc[8][16][512];   // 128 KB: 8 cached weight slots
  int lane = threadIdx.x & 63, w = threadIdx.x >> 6;   // w: 0..15
  int l16 = lane & 15, lq = lane >> 4;
  int nb = blockIdx.x * 32;

  for (int i = threadIdx.x; i < 32*256; i += 1024){
    int row = i >> 8, c = i & 255;
    int sc = (((c >> 3) ^ (row & 7)) << 3) | (c & 7);
    hbuf[row][sc] = (c < 252) ? (f16)h0[c] : (f16)0.f;
  }

  int j = w*16 + l16;
  bool jv = (j < 252);
  int js = jv ? j : 251;
  float bR = biasc[js], bZ = biasc[252+js], bI = biasc[504+js], bH = biasc[756+js];
  const f16* pR = BgT + (size_t)(0*256 + j)*352 + lq*8;
  const f16* pZ = BgT + (size_t)(1*256 + j)*352 + lq*8;
  const f16* pI = BgT + (size_t)(2*256 + j)*352 + lq*8;
  const f16* pH = BgT + (size_t)(3*256 + j)*352 + lq*8;
  const f16* xp0 = x16t + ((size_t)nb + l16)*96 + lq*8;        // + t*4096*96 + u*32
  const f16* xp1 = x16t + ((size_t)nb + 16 + l16)*96 + lq*8;

  // populate the persistent weight cache (once):
  // slots 0..2 = u0 R/Z/I, 3..5 = u1 R/Z/I, 6..7 = u2 R/Z
  *(f16x8*)&wc[0][w][lane*8] = *(const f16x8*)(pR);
  *(f16x8*)&wc[1][w][lane*8] = *(const f16x8*)(pZ);
  *(f16x8*)&wc[2][w][lane*8] = *(const f16x8*)(pI);
  *(f16x8*)&wc[3][w][lane*8] = *(const f16x8*)(pR + 32);
  *(f16x8*)&wc[4][w][lane*8] = *(const f16x8*)(pZ + 32);
  *(f16x8*)&wc[5][w][lane*8] = *(const f16x8*)(pI + 32);
  *(f16x8*)&wc[6][w][lane*8] = *(const f16x8*)(pR + 64);
  *(f16x8*)&wc[7][w][lane*8] = *(const f16x8*)(pZ + 64);

  float hown[2][4];   // [mf][r]
  int idxr[2][4];
  #pragma unroll
  for (int mf = 0; mf < 2; ++mf)
  #pragma unroll
  for (int r = 0; r < 4; ++r){
    hown[mf][r] = jv ? h0[js] : 0.f;
    idxr[mf][r] = idxp[nb + mf*16 + lq*4 + r];
  }

  __syncthreads();

#define NTL(p) __builtin_nontemporal_load((const f16x8*)(p))

  for (int t = 0; t < 48; ++t){
    f32x4 z4 = {0.f,0.f,0.f,0.f};
    f32x4 aR[2] = {z4,z4}, aZ[2] = {z4,z4}, aI[2] = {z4,z4}, aH[2] = {z4,z4};
    size_t xt = (size_t)t*4096*96;

    // pinned 4-slot rotating pipeline over the STREAMED fragments
    // (u=2: I only; u=3..10: R,Z,M). All streamed loads are non-temporal.
    f16x8 R0,Z0,M0, R1,Z1,M1, R2,Z2,M2, R3,Z3,M3;
#define PIN3(s) asm volatile("" :: "v"(*(const f32x4*)&R##s), \
                                   "v"(*(const f32x4*)&Z##s), \
                                   "v"(*(const f32x4*)&M##s))
#define PIN1(s) asm volatile("" :: "v"(*(const f32x4*)&M##s))
#define LW(s,u) do{ \
      R##s = NTL(pR + (u)*32); \
      Z##s = NTL(pZ + (u)*32); \
      M##s = NTL(pH + (u)*32); \
      PIN3(s); }while(0)
#define LW1(s) do{ \
      M##s = NTL(pI + 64); \
      PIN1(s); }while(0)
#define MM(u, wR_, wZ_, wM_, a0, a1) do{ \
      aR[0] = MFMA(a0, wR_, aR[0]);  aR[1] = MFMA(a1, wR_, aR[1]); \
      aZ[0] = MFMA(a0, wZ_, aZ[0]);  aZ[1] = MFMA(a1, wZ_, aZ[1]); \
      if ((u) < 3){ aI[0] = MFMA(a0, wM_, aI[0]);  aI[1] = MFMA(a1, wM_, aI[1]); } \
      else        { aH[0] = MFMA(a0, wM_, aH[0]);  aH[1] = MFMA(a1, wM_, aH[1]); } \
    }while(0)
#define STEP(s,u) do{ \
      int chunk = ((u) - 3)*4 + lq; \
      f16x8 a0 = *(const f16x8*)(&hbuf[l16][(chunk ^ (l16 & 7)) << 3]); \
      f16x8 a1 = *(const f16x8*)(&hbuf[16 + l16][(chunk ^ (l16 & 7)) << 3]); \
      MM(u, R##s, Z##s, M##s, a0, a1); \
    }while(0)
#define STEP_L(u) do{ \
      f16x8 wR_ = *(const f16x8*)&wc[(u)*3+0][w][lane*8]; \
      f16x8 wZ_ = *(const f16x8*)&wc[(u)*3+1][w][lane*8]; \
      f16x8 wM_ = *(const f16x8*)&wc[(u)*3+2][w][lane*8]; \
      f16x8 a0 = *(const f16x8*)(xp0 + xt + (u)*32); \
      f16x8 a1 = *(const f16x8*)(xp1 + xt + (u)*32); \
      MM(u, wR_, wZ_, wM_, a0, a1); \
    }while(0)
#define STEP2(s) do{ \
      f16x8 wR_ = *(const f16x8*)&wc[6][w][lane*8]; \
      f16x8 wZ_ = *(const f16x8*)&wc[7][w][lane*8]; \
      f16x8 a0 = *(const f16x8*)(xp0 + xt + 64); \
      f16x8 a1 = *(const f16x8*)(xp1 + xt + 64); \
      MM(2, wR_, wZ_, M##s, a0, a1); \
    }while(0)

    LW1(0); LW(1,3); LW(2,4); LW(3,5);
    STEP_L(0);
    STEP_L(1);
    STEP2(0);    LW(0,6);
    STEP(1,3);   LW(1,7);
    STEP(2,4);   LW(2,8);
    STEP(3,5);   LW(3,9);
    STEP(0,6);   LW(0,10);
    STEP(1,7);
    STEP(2,8);
    STEP(3,9);
    STEP(0,10);
#undef LW
#undef LW1
#undef STEP
#undef STEP_L
#undef STEP2
#undef MM
#undef PIN3
#undef PIN1

    __syncthreads();   // all h reads for step t complete

    // epilogue: gate math, write hbuf (swizzled) + xstar/xs16 on last valid step
    #pragma unroll
    for (int mf = 0; mf < 2; ++mf)
    #pragma unroll
    for (int r = 0; r < 4; ++r){
      int row = mf*16 + lq*4 + r;
      float rr = sigm(aR[mf][r] + bR);
      float zz = sigm(aZ[mf][r] + bZ);
      float ng = tanh_f(aI[mf][r] + bI + rr*(aH[mf][r] + bH));
      float hnew = (1.f - zz)*ng + zz*hown[mf][r];
      hnew = jv ? hnew : 0.f;
      hown[mf][r] = hnew;
      int sc = (((j >> 3) ^ (row & 7)) << 3) | (j & 7);
      hbuf[row][sc] = (f16)hnew;
      if (jv && idxr[mf][r] == t){
        xstar[((size_t)(nb + row) << 8) + j] = hnew;
        xs16[((size_t)(nb + row) << 8) + j] = (f16)hnew;
      }
    }
    __syncthreads();   // h writes visible before step t+1 reads
  }
#undef NTL
}

// ---------------- demo cols of x_star (c 252..255), f32 + f16 ----------------
__global__ __launch_bounds__(256) void k_xdemo(const float* __restrict__ x_demo,
    float* __restrict__ xs32, f16* __restrict__ xs16)
{
  int id = blockIdx.x*256 + threadIdx.x;   // 4096*4
  int n = id >> 2, c = id & 3;
  float v = x_demo[id];
  xs32[((size_t)n << 8) + 252 + c] = v;
  xs16[((size_t)n << 8) + 252 + c] = (f16)v;
}

// ---------------- fused q+k projections (one launch) ----------------
__global__ __launch_bounds__(256) void k_projqk(const f16* __restrict__ xs16,
    const f16* __restrict__ wq16, const f16* __restrict__ wk16,
    const float* __restrict__ bq, const float* __restrict__ bk,
    const float* __restrict__ wo, f16* __restrict__ qf, f16* __restrict__ kf)
{
  int lane = threadIdx.x & 63, wv = threadIdx.x >> 6;
  int l16 = lane & 15, lq = lane >> 4;
  int nb = blockIdx.x * 64;
  int mode = blockIdx.y >> 2;           // 0: q, 1: k
  int yy = blockIdx.y & 3;
  const f16* w16 = mode ? wk16 : wq16;
  const float* bias = mode ? bk : bq;
  f16* out16 = mode ? kf : qf;
  int ocol = yy*64 + wv*16 + l16;
  f32x4 z4 = {0.f,0.f,0.f,0.f};
  f32x4 acc[4] = {z4,z4,z4,z4};
  #pragma unroll
  for (int ks = 0; ks < 8; ++ks){
    f16x8 b = *(const f16x8*)(w16 + (size_t)ocol*256 + ks*32 + lq*8);
    #pragma unroll
    for (int mi = 0; mi < 4; ++mi){
      f16x8 a = *(const f16x8*)(xs16 + (size_t)(nb + mi*16 + l16)*256 + ks*32 + lq*8);
      acc[mi] = MFMA(a, b, acc[mi]);
    }
  }
  float badd = bias[ocol];
  float scale = mode ? 1.f : wo[ocol >> 6]*0.125f;
  #pragma unroll
  for (int mi = 0; mi < 4; ++mi)
  #pragma unroll
  for (int r = 0; r < 4; ++r){
    int n = nb + mi*16 + lq*4 + r;
    float v = acc[mi][r] + badd;
    if (!mode) v *= scale;
    out16[(size_t)n*256 + ocol] = (f16)v;
  }
}

// ---------------- scores GEMM: 128x128 block tile, wave = 64x64 ----------------
__global__ __launch_bounds__(256) void k_scores(const f16* __restrict__ qf,
    const f16* __restrict__ kf, uint16_t* __restrict__ sco)
{
  int lane = threadIdx.x & 63, w = threadIdx.x >> 6;
  int l16 = lane & 15, lq = lane >> 4;
  int mh = w >> 1, jh = w & 1;
  int nb = blockIdx.x*128 + mh*64;
  int mb = blockIdx.y*128 + jh*64;
  f32x4 z4 = {0.f,0.f,0.f,0.f};
  f32x4 acc[4][4];
  #pragma unroll
  for (int i = 0; i < 4; ++i)
  #pragma unroll
  for (int j = 0; j < 4; ++j) acc[i][j] = z4;
  #pragma unroll
  for (int ks = 0; ks < 8; ++ks){
    f16x8 a[4], b[4];
    #pragma unroll
    for (int i = 0; i < 4; ++i){
      a[i] = *(const f16x8*)(qf + (size_t)(nb + i*16 + l16)*256 + ks*32 + lq*8);
      b[i] = *(const f16x8*)(kf + (size_t)(mb + i*16 + l16)*256 + ks*32 + lq*8);
    }
    #pragma unroll
    for (int mi = 0; mi < 4; ++mi)
    #pragma unroll
    for (int jf = 0; jf < 4; ++jf)
      acc[mi][jf] = MFMA(a[mi], b[jf], acc[mi][jf]);
  }
  #pragma unroll
  for (int mi = 0; mi < 4; ++mi)
  #pragma unroll
  for (int jf = 0; jf < 4; ++jf)
  #pragma unroll
  for (int r = 0; r < 4; ++r){
    int n = nb + mi*16 + lq*4 + r;
    int m = mb + jf*16 + l16;
    sco[((size_t)n << 12) + m] = f2bf(acc[mi][jf][r]);
  }
}

// ---------------- fused softmax stats + flags + degrees (block per row) ----------------
__global__ __launch_bounds__(256) void k_adj(const uint16_t* __restrict__ sco,
    const float* __restrict__ mask_edge, const float* __restrict__ phip,
    uint8_t* __restrict__ flags, float* __restrict__ sadj,
    float* __restrict__ dinv, float* __restrict__ dinva)
{
  int n = blockIdx.x;
  int lane = threadIdx.x & 63, wv = threadIdx.x >> 6;
  const uint16_t* row = sco + ((size_t)n << 12);
  int base = threadIdx.x * 16;
  const uint4* p = (const uint4*)(row + base);
  uint4 w0 = p[0], w1 = p[1];
  uint32_t ws_[8] = {w0.x,w0.y,w0.z,w0.w,w1.x,w1.y,w1.z,w1.w};
  float v[16];
  #pragma unroll
  for (int i = 0; i < 8; ++i){
    v[2*i]   = bf2f((uint16_t)(ws_[i] & 0xffffu));
    v[2*i+1] = bf2f((uint16_t)(ws_[i] >> 16));
  }
  float mx = v[0];
  #pragma unroll
  for (int i = 1; i < 16; ++i) mx = fmaxf(mx, v[i]);
  #pragma unroll
  for (int o = 32; o >= 1; o >>= 1) mx = fmaxf(mx, __shfl_xor(mx, o));
  __shared__ float redA[4], redB[4], redC[4], redD[4];
  if (lane == 0) redA[wv] = mx;
  __syncthreads();
  mx = fmaxf(fmaxf(redA[0], redA[1]), fmaxf(redA[2], redA[3]));
  float s = 0.f;
  #pragma unroll
  for (int i = 0; i < 16; ++i){ v[i] = __expf(v[i] - mx); s += v[i]; }
  #pragma unroll
  for (int o = 32; o >= 1; o >>= 1) s += __shfl_xor(s, o);
  if (lane == 0) redB[wv] = s;
  __syncthreads();
  float rs = 1.f / (redB[0] + redB[1] + redB[2] + redB[3]);
  float phi = phip[0];
  uint32_t by[16]; int c0 = 0, c1 = 0;
  #pragma unroll
  for (int e = 0; e < 16; ++e){
    float a = v[e] * rs;
    int col = base + e;
    uint32_t b = (a >= phi && col != n) ? 1u : 0u;
    if (b){ if (mask_edge[((size_t)n << 12) + col] >= 0.1f) b |= 2u; }
    by[e] = b;
    c0 += (int)(b & 1u);
    c1 += (int)(b >> 1);
  }
  uint4 pk;
  pk.x = by[0]  | (by[1]  << 8) | (by[2]  << 16) | (by[3]  << 24);
  pk.y = by[4]  | (by[5]  << 8) | (by[6]  << 16) | (by[7]  << 24);
  pk.z = by[8]  | (by[9]  << 8) | (by[10] << 16) | (by[11] << 24);
  pk.w = by[12] | (by[13] << 8) | (by[14] << 16) | (by[15] << 24);
  *(uint4*)(flags + ((size_t)n << 12) + base) = pk;
  float f0 = (float)c0, f1 = (float)c1;
  #pragma unroll
  for (int o = 32; o >= 1; o >>= 1){ f0 += __shfl_xor(f0, o); f1 += __shfl_xor(f1, o); }
  if (lane == 0){ redC[wv] = f0; redD[wv] = f1; }
  __syncthreads();
  if (threadIdx.x == 0){
    float d0 = redC[0]+redC[1]+redC[2]+redC[3];
    float d1 = redD[0]+redD[1]+redD[2]+redD[3];
    sadj[n] = d0;
    dinv[n]  = rsqrtf(1.f + d0);
    dinva[n] = rsqrtf(1.f + d1);
  }
}

// ---------------- xw = xs@gcn_w ; y = dinv*xw (fp16) ----------------
__global__ __launch_bounds__(256) void k_xw_y(const f16* __restrict__ xs16,
    const f16* __restrict__ gw16, const float* __restrict__ dinv,
    const float* __restrict__ dinva, f16* __restrict__ y16, f16* __restrict__ ya16)
{
  int lane = threadIdx.x & 63, wv = threadIdx.x >> 6;
  int l16 = lane & 15, lq = lane >> 4;
  int nb = blockIdx.x * 64;
  int jcol = blockIdx.y*64 + wv*16 + l16;
  f32x4 z4 = {0.f,0.f,0.f,0.f};
  f32x4 acc[4] = {z4,z4,z4,z4};
  #pragma unroll
  for (int ks = 0; ks < 8; ++ks){
    f16x8 b = *(const f16x8*)(gw16 + (size_t)jcol*256 + ks*32 + lq*8);
    #pragma unroll
    for (int mi = 0; mi < 4; ++mi){
      f16x8 a = *(const f16x8*)(xs16 + (size_t)(nb + mi*16 + l16)*256 + ks*32 + lq*8);
      acc[mi] = MFMA(a, b, acc[mi]);
    }
  }
  #pragma unroll
  for (int mi = 0; mi < 4; ++mi)
  #pragma unroll
  for (int r = 0; r < 4; ++r){
    int n = nb + mi*16 + lq*4 + r;
    float v = acc[mi][r];
    y16[(size_t)n*256 + jcol]  = (f16)(dinv[n]*v);
    ya16[(size_t)n*256 + jcol] = (f16)(dinva[n]*v);
  }
}

// ---------------- GCN gather: both variants in one block ----------------
__global__ __launch_bounds__(256) void k_zgather(const uint8_t* __restrict__ flags,
    const f16* __restrict__ y16, const f16* __restrict__ ya16,
    const float* __restrict__ dinv, const float* __restrict__ dinva,
    const float* __restrict__ gcn_b, float* __restrict__ z32, float* __restrict__ za32)
{
  int n = blockIdx.x;
  int lane = threadIdx.x & 63, wv = threadIdx.x >> 6;
  uint4 w = ((const uint4*)(flags + ((size_t)n << 12)))[threadIdx.x];
  uint32_t m0[4] = {w.x & 0x01010101u, w.y & 0x01010101u, w.z & 0x01010101u, w.w & 0x01010101u};
  uint32_t m1[4] = {w.x & 0x02020202u, w.y & 0x02020202u, w.z & 0x02020202u, w.w & 0x02020202u};
  int c0 = __popc(m0[0]) + __popc(m0[1]) + __popc(m0[2]) + __popc(m0[3]);
  int c1 = __popc(m1[0]) + __popc(m1[1]) + __popc(m1[2]) + __popc(m1[3]);
  int v0 = c0, v1 = c1;
  #pragma unroll
  for (int o = 1; o < 64; o <<= 1){
    int u0 = __shfl_up(v0, o), u1 = __shfl_up(v1, o);
    if (lane >= o){ v0 += u0; v1 += u1; }
  }
  __shared__ int wsum0[4], wsum1[4];
  if (lane == 63){ wsum0[wv] = v0; wsum1[wv] = v1; }
  __syncthreads();
  int pos0 = v0 - c0, pos1 = v1 - c1;
  #pragma unroll
  for (int i = 0; i < 4; ++i) if (i < wv){ pos0 += wsum0[i]; pos1 += wsum1[i]; }
  int tot0 = wsum0[0]+wsum0[1]+wsum0[2]+wsum0[3];
  int tot1 = wsum1[0]+wsum1[1]+wsum1[2]+wsum1[3];
  __shared__ uint16_t list0[4096];
  __shared__ uint16_t list1[4096];
  int cbase = threadIdx.x * 16;
  #pragma unroll
  for (int q = 0; q < 4; ++q){
    uint32_t m = m0[q];
    while (m){
      int b = __ffs(m) - 1;
      list0[pos0++] = (uint16_t)(cbase + q*4 + (b >> 3));
      m &= m - 1;
    }
    m = m1[q];
    while (m){
      int b = __ffs(m) - 1;
      list1[pos1++] = (uint16_t)(cbase + q*4 + (b >> 3));
      m &= m - 1;
    }
  }
  __syncthreads();
  int j = threadIdx.x;
  float acc0 = (float)y16[((size_t)n << 8) + j];
  float acc1 = (float)ya16[((size_t)n << 8) + j];
  for (int i = 0; i < tot0; ++i) acc0 += (float)y16[((size_t)list0[i] << 8) + j];
  for (int i = 0; i < tot1; ++i) acc1 += (float)ya16[((size_t)list1[i] << 8) + j];
  z32[((size_t)n << 8) + j]  = dinv[n]*acc0 + gcn_b[j];
  za32[((size_t)n << 8) + j] = dinva[n]*acc1 + gcn_b[j];
}

// ---------------- clustering: qsoft, labels, colsum ----------------
__global__ __launch_bounds__(256) void k_cluster(const float* __restrict__ xs32,
    const float* __restrict__ centers, float* __restrict__ qsoft,
    int* __restrict__ labels, float* __restrict__ colsum)
{
  int nb = blockIdx.x * 16;
  __shared__ float xs[16][256];
  __shared__ float ct[2560];   // transposed [d][k]
  __shared__ float d2s[16][10];
  __shared__ float qs[16][10];
  for (int i = threadIdx.x; i < 16*256; i += 256) xs[i >> 8][i & 255] = xs32[(size_t)nb*256 + i];
  for (int i = threadIdx.x; i < 2560; i += 256){ int k = i >> 8, d = i & 255; ct[d*10 + k] = centers[i]; }
  __syncthreads();
  if (threadIdx.x < 160){
    int r = threadIdx.x / 10, k = threadIdx.x % 10;
    float s = 0.f;
    for (int d = 0; d < 256; ++d){ float df = xs[r][d] - ct[d*10 + k]; s += df*df; }
    d2s[r][k] = s;
  }
  __syncthreads();
  if (threadIdx.x < 16){
    int r = threadIdx.x;
    float un[10]; float tot = 0.f;
    #pragma unroll
    for (int k = 0; k < 10; ++k){ un[k] = 1.f/(1.f + d2s[r][k]); tot += un[k]; }
    float inv = 1.f / tot;
    int best = 0; float bm = un[0];
    #pragma unroll
    for (int k = 1; k < 10; ++k){ if (un[k] > bm){ bm = un[k]; best = k; } }
    labels[nb + r] = best;
    #pragma unroll
    for (int k = 0; k < 10; ++k){ float q = un[k]*inv; qs[r][k] = q; qsoft[(size_t)(nb + r)*10 + k] = q; }
  }
  __syncthreads();
  if (threadIdx.x < 10){
    int k = threadIdx.x; float s = 0.f;
    #pragma unroll
    for (int r = 0; r < 16; ++r) s += qs[r][k];
    atomicAdd(&colsum[k], s);
  }
}

// ---------------- KL loss ----------------
__global__ __launch_bounds__(256) void k_kl(const float* __restrict__ qsoft,
    const float* __restrict__ colsum, float* __restrict__ klsum)
{
  int n = blockIdx.x*256 + threadIdx.x;
  float p[10]; float s = 0.f;
  #pragma unroll
  for (int k = 0; k < 10; ++k){
    float q = qsoft[(size_t)n*10 + k];
    float pu = q*q/colsum[k];
    p[k] = pu; s += pu;
  }
  float inv = 1.f/s; float kl = 0.f;
  #pragma unroll
  for (int k = 0; k < 10; ++k){
    float pk = p[k]*inv;
    float q = qsoft[(size_t)n*10 + k];
    kl += pk*__logf(pk/(q + 1e-6f));
  }
  int lane = threadIdx.x & 63, wv = threadIdx.x >> 6;
  #pragma unroll
  for (int o = 32; o >= 1; o >>= 1) kl += __shfl_xor(kl, o);
  __shared__ float red[4];
  if (lane == 0) red[wv] = kl;
  __syncthreads();
  if (threadIdx.x == 0) atomicAdd(klsum, red[0]+red[1]+red[2]+red[3]);
}

// ---------------- FFN + l2-normalize ----------------
__global__ __launch_bounds__(128) void k_ffn(const float* __restrict__ z32,
    const float* __restrict__ za32, const float* __restrict__ ffn_w,
    const float* __restrict__ ffn_b, f16* __restrict__ zn16, f16* __restrict__ zan16)
{
  int n = blockIdx.x; int aug = blockIdx.y;
  const float* z = (aug ? za32 : z32) + ((size_t)n << 8);
  __shared__ float zr[256];
  zr[threadIdx.x] = z[threadIdx.x];
  zr[threadIdx.x + 128] = z[threadIdx.x + 128];
  __syncthreads();
  int j = threadIdx.x;
  float acc = ffn_b[j];
  #pragma unroll 8
  for (int d = 0; d < 256; ++d) acc += zr[d]*ffn_w[d*128 + j];
  float ss = acc*acc;
  int lane = threadIdx.x & 63, wv = threadIdx.x >> 6;
  #pragma unroll
  for (int o = 32; o >= 1; o >>= 1) ss += __shfl_xor(ss, o);
  __shared__ float sred[2];
  if (lane == 0) sred[wv] = ss;
  __syncthreads();
  float tot = sred[0] + sred[1];
  float rn = 1.f / fmaxf(sqrtf(tot), 1e-12f);
  (aug ? zan16 : zn16)[((size_t)n << 7) + j] = (f16)(acc*rn);
}

// ---------------- contrastive loss partial sums ----------------
__global__ __launch_bounds__(256) void k_closs(const f16* __restrict__ zn,
    const f16* __restrict__ zan, const uint8_t* __restrict__ flags,
    const int* __restrict__ labels,
    float* __restrict__ rs1, float* __restrict__ rs2, float* __restrict__ rsA,
    float* __restrict__ rsC, float* __restrict__ rcC, float* __restrict__ rdI,
    float* __restrict__ rdi)
{
  int lane = threadIdx.x & 63;
  int ji = threadIdx.x >> 6;
  int l16 = lane & 15, lq = lane >> 4;
  int nb = blockIdx.x * 32;
  int mstart = blockIdx.y * 512;
  f16x8 A[2][4];
  #pragma unroll
  for (int mi = 0; mi < 2; ++mi)
  #pragma unroll
  for (int ks = 0; ks < 4; ++ks)
    A[mi][ks] = *(const f16x8*)(zn + (size_t)(nb + mi*16 + l16)*128 + ks*32 + lq*8);
  int labn[8];
  #pragma unroll
  for (int i = 0; i < 8; ++i) labn[i] = labels[nb + (i >> 2)*16 + lq*4 + (i & 3)];
  float a1[8]={}, a2[8]={}, aA[8]={}, aC[8]={}, aCc[8]={}, adI[8]={}, adi[8]={};
  uint8_t fA[8]; int labA;
  {
    int mcol0 = mstart + ji*16 + l16;
    #pragma unroll
    for (int i = 0; i < 8; ++i){
      int n = nb + (i >> 2)*16 + lq*4 + (i & 3);
      fA[i] = flags[((size_t)n << 12) + mcol0];
    }
    labA = labels[mcol0];
  }
  #pragma unroll
  for (int tile = 0; tile < 8; ++tile){
    int mcol = mstart + tile*64 + ji*16 + l16;
    uint8_t fB[8]; int labB = 0;
    if (tile < 7){
      int mn = mcol + 64;
      #pragma unroll
      for (int i = 0; i < 8; ++i){
        int n = nb + (i >> 2)*16 + lq*4 + (i & 3);
        fB[i] = flags[((size_t)n << 12) + mn];
      }
      labB = labels[mn];
    }
    f32x4 z4 = {0.f,0.f,0.f,0.f};
    f32x4 acc1[2] = {z4, z4};
    f32x4 acc2[2] = {z4, z4};
    #pragma unroll
    for (int ks = 0; ks < 4; ++ks){
      f16x8 b1 = *(const f16x8*)(zn  + (size_t)mcol*128 + ks*32 + lq*8);
      f16x8 b2 = *(const f16x8*)(zan + (size_t)mcol*128 + ks*32 + lq*8);
      #pragma unroll
      for (int mi = 0; mi < 2; ++mi){
        acc1[mi] = MFMA(A[mi][ks], b1, acc1[mi]);
        acc2[mi] = MFMA(A[mi][ks], b2, acc2[mi]);
      }
    }
    #pragma unroll
    for (int mi = 0; mi < 2; ++mi)
    #pragma unroll
    for (int r = 0; r < 4; ++r){
      int i8 = mi*4 + r;
      int n = nb + mi*16 + lq*4 + r;
      float e1 = __expf(2.f*acc1[mi][r]);
      float e2 = __expf(2.f*acc2[mi][r]);
      uint8_t fl = fA[i8];
      a1[i8] += e1; a2[i8] += e2;
      bool adjb = (fl & 1);
      if (adjb) aA[i8] += e1;
      if (!adjb && labn[i8] == labA && n != mcol){ aC[i8] += e1; aCc[i8] += 1.f; }
      if (n == mcol){ adI[i8] += e2; adi[i8] += e1; }
    }
    if (tile < 7){
      #pragma unroll
      for (int i = 0; i < 8; ++i) fA[i] = fB[i];
      labA = labB;
    }
  }
  #pragma unroll
  for (int i = 0; i < 8; ++i){
    #pragma unroll
    for (int o = 1; o < 16; o <<= 1){
      a1[i]  += __shfl_xor(a1[i], o);  a2[i]  += __shfl_xor(a2[i], o);
      aA[i]  += __shfl_xor(aA[i], o);  aC[i]  += __shfl_xor(aC[i], o);
      aCc[i] += __shfl_xor(aCc[i], o); adI[i] += __shfl_xor(adI[i], o);
      adi[i] += __shfl_xor(adi[i], o);
    }
  }
  if (l16 == 0){
    #pragma unroll
    for (int i = 0; i < 8; ++i){
      int n = nb + (i >> 2)*16 + lq*4 + (i & 3);
      atomicAdd(&rs1[n], a1[i]);  atomicAdd(&rs2[n], a2[i]);
      atomicAdd(&rsA[n], aA[i]);  atomicAdd(&rsC[n], aC[i]);
      atomicAdd(&rcC[n], aCc[i]); atomicAdd(&rdI[n], adI[i]);
      atomicAdd(&rdi[n], adi[i]);
    }
  }
}

// ---------------- contrastive loss finalize ----------------
__global__ __launch_bounds__(256) void k_clfinal(const float* __restrict__ rs1,
    const float* __restrict__ rs2, const float* __restrict__ rsA,
    const float* __restrict__ rsC, const float* __restrict__ rcC,
    const float* __restrict__ rdI, const float* __restrict__ rdi,
    const float* __restrict__ sadj, float* __restrict__ clsum)
{
  int n = blockIdx.x*256 + threadIdx.x;
  float pos = rdI[n] + rsA[n] + rsC[n];
  float den = rs1[n] + rs2[n] - rdi[n];
  float cnt = sadj[n] + rcC[n] + 1.f;
  float v = __logf(pos/den)/cnt;
  int lane = threadIdx.x & 63, wv = threadIdx.x >> 6;
  #pragma unroll
  for (int o = 32; o >= 1; o >>= 1) v += __shfl_xor(v, o);
  __shared__ float red[4];
  if (lane == 0) red[wv] = v;
  __syncthreads();
  if (threadIdx.x == 0) atomicAdd(clsum, red[0]+red[1]+red[2]+red[3]);
}

__global__ void k_loss(const float* __restrict__ scal, float* __restrict__ out){
  out[8192] = scal[0]*(1.f/4096.f) - scal[1];
}

// ---------------- output head (wave per row) ----------------
__global__ __launch_bounds__(256) void k_outhead(const float* __restrict__ z32,
    const float* __restrict__ pre_w, const float* __restrict__ pre_b,
    float* __restrict__ out)
{
  int lane = threadIdx.x & 63, wv = threadIdx.x >> 6;
  int n = blockIdx.x*4 + wv;
  float4 zv = *(const float4*)(z32 + ((size_t)n << 8) + lane*4);
  float4 w0 = *(const float4*)(pre_w + lane*8);
  float4 w1 = *(const float4*)(pre_w + lane*8 + 4);
  float c0 = zv.x*w0.x + zv.y*w0.z + zv.z*w1.x + zv.w*w1.z;
  float c1 = zv.x*w0.y + zv.y*w0.w + zv.z*w1.y + zv.w*w1.w;
  #pragma unroll
  for (int o = 32; o >= 1; o >>= 1){ c0 += __shfl_xor(c0, o); c1 += __shfl_xor(c1, o); }
  if (lane == 0){
    out[(size_t)n*2]     = c0 + pre_b[0];
    out[(size_t)n*2 + 1] = c1 + pre_b[1];
  }
}

// ---------------- host launch ----------------
extern "C" void kernel_launch(void* const* d_in, const int* in_sizes, int n_in,
                              void* d_out, int out_size, void* d_ws, size_t ws_size,
                              hipStream_t stream)
{
  const float* x         = (const float*)d_in[0];
  const float* x_demo    = (const float*)d_in[1];
  const int*   slen      = (const int*)d_in[2];
  const float* mask_edge = (const float*)d_in[3];
  const float* w_ih      = (const float*)d_in[4];
  const float* w_hh      = (const float*)d_in[5];
  const float* b_ih      = (const float*)d_in[6];
  const float* b_hh      = (const float*)d_in[7];
  const float* h0        = (const float*)d_in[8];
  const float* wq        = (const float*)d_in[9];
  const float* bq        = (const float*)d_in[10];
  const float* wk        = (const float*)d_in[11];
  const float* bk        = (const float*)d_in[12];
  const float* wo        = (const float*)d_in[13];
  const float* phi       = (const float*)d_in[15];
  const float* centers   = (const float*)d_in[16];
  const float* gcn_w     = (const float*)d_in[17];
  const float* gcn_b     = (const float*)d_in[18];
  const float* ffn_w     = (const float*)d_in[19];
  const float* ffn_b     = (const float*)d_in[20];
  const float* pre_w     = (const float*)d_in[21];
  const float* pre_b     = (const float*)d_in[22];
  float* out = (float*)d_out;

  size_t off = 0;
  char* base = (char*)d_ws;
  auto take = [&](size_t bytes)->void*{
    void* p = base + off;
    off += (bytes + 255) & ~(size_t)255;
    return p;
  };
  f16*   BgT    = (f16*)take((size_t)4*256*352*2);
  f16*   wq16   = (f16*)take((size_t)65536*2);
  f16*   wk16   = (f16*)take((size_t)65536*2);
  f16*   gw16   = (f16*)take((size_t)65536*2);
  float* biasc  = (float*)take(1008*4);
  int*   idx    = (int*)take(4096*4);
  float* xs32   = (float*)take((size_t)4096*256*4);
  f16*   xs16   = (f16*)take((size_t)4096*256*2);
  f16*   qf16   = (f16*)take((size_t)4096*256*2);
  f16*   kf16   = (f16*)take((size_t)4096*256*2);
  uint16_t* sco = (uint16_t*)take((size_t)4096*4096*2);
  uint8_t* flags= (uint8_t*)take((size_t)4096*4096);
  float* sadj   = (float*)take(4096*4);
  float* dinv   = (float*)take(4096*4);
  float* dinva  = (float*)take(4096*4);
  f16*   y16    = (f16*)take((size_t)4096*256*2);
  f16*   ya16   = (f16*)take((size_t)4096*256*2);
  float* z32    = (float*)take((size_t)4096*256*4);
  float* za32   = (float*)take((size_t)4096*256*4);
  f16*   zn16   = (f16*)take((size_t)4096*128*2);
  f16*   zan16  = (f16*)take((size_t)4096*128*2);
  float* qsoft  = (float*)take((size_t)4096*10*4);
  int*   labels = (int*)take(4096*4);
  float* colsum = (float*)take(64);
  float* scal   = (float*)take(64);         // [0]=klsum, [1]=clsum
  float* rsbuf  = (float*)take((size_t)7*4096*4);
  float* rs1 = rsbuf,        *rs2 = rsbuf + 4096, *rsA = rsbuf + 2*4096;
  float* rsC = rsbuf + 3*4096, *rcC = rsbuf + 4*4096;
  float* rdI = rsbuf + 5*4096, *rdi = rsbuf + 6*4096;

  // x16t[48][4096][96] fp16 (37.75 MB) aliases sco(33.55MB)+flags head:
  // x16t is only live during the GRU; sco/flags are written strictly after.
  f16* x16t = (f16*)sco;

  hipMemsetAsync(colsum, 0, 64, stream);
  hipMemsetAsync(scal, 0, 64, stream);
  hipMemsetAsync(rsbuf, 0, (size_t)7*4096*4, stream);

  k_prep<<<2196, 256, 0, stream>>>(w_ih, w_hh, b_ih, b_hh, slen, wq, wk, gcn_w,
                                   BgT, wq16, wk16, gw16, biasc, idx);
  k_xt<<<9216, 256, 0, stream>>>(x, x16t);
  k_xdemo<<<64, 256, 0, stream>>>(x_demo, xs32, xs16);
  k_gru_all<<<128, 1024, 0, stream>>>(x16t, BgT, biasc, h0, idx, xs32, xs16);
  k_projqk<<<dim3(64, 8), 256, 0, stream>>>(xs16, wq16, wk16, bq, bk, wo, qf16, kf16);
  k_scores<<<dim3(32, 32), 256, 0, stream>>>(qf16, kf16, sco);
  k_adj<<<4096, 256, 0, stream>>>(sco, mask_edge, phi, flags, sadj, dinv, dinva);
  k_xw_y<<<dim3(64, 4), 256, 0, stream>>>(xs16, gw16, dinv, dinva, y16, ya16);
  k_zgather<<<4096, 256, 0, stream>>>(flags, y16, ya16, dinv, dinva, gcn_b, z32, za32);
  k_cluster<<<256, 256, 0, stream>>>(xs32, centers, qsoft, labels, colsum);
  k_kl<<<16, 256, 0, stream>>>(qsoft, colsum, &scal[0]);
  k_ffn<<<dim3(4096, 2), 128, 0, stream>>>(z32, za32, ffn_w, ffn_b, zn16, zan16);
  k_closs<<<dim3(128, 8), 256, 0, stream>>>(zn16, zan16, flags, labels,
                                            rs1, rs2, rsA, rsC, rcC, rdI, rdi);
  k_clfinal<<<16, 256, 0, stream>>>(rs1, rs2, rsA, rsC, rcC, rdI, rdi, sadj, &scal[1]);
  k_loss<<<1, 1, 0, stream>>>(scal, out);
  k_outhead<<<1024, 256, 0, stream>>>(z32, pre_w, pre_b, out);

  (void)in_sizes; (void)n_in; (void)out_size; (void)ws_size;
}

// Round 16
// 823.786 us; speedup vs baseline: 1.3455x; 1.3455x over previous
//
#include <hip/hip_runtime.h>
#include <cstdint>
#include <cstddef>

// ---------------- types / helpers ----------------
typedef _Float16 f16;
typedef f16 f16x8 __attribute__((ext_vector_type(8)));
typedef float f32x4 __attribute__((ext_vector_type(4)));

#define MFMA(a,b,c) __builtin_amdgcn_mfma_f32_16x16x32_f16(a,b,c,0,0,0)

__device__ __forceinline__ float sigm(float x){ return 1.f/(1.f+__expf(-x)); }
__device__ __forceinline__ float tanh_f(float x){
  float a = __expf(-2.f*fabsf(x));
  float t = (1.f-a)/(1.f+a);
  return x >= 0.f ? t : -t;
}
__device__ __forceinline__ uint16_t f2bf(float f){
  uint32_t u = __float_as_uint(f);
  return (uint16_t)((u + 0x7fffu + ((u>>16)&1u)) >> 16);
}
__device__ __forceinline__ float bf2f(uint16_t h){
  return __uint_as_float(((uint32_t)h) << 16);
}

// ---------------- prep: weights repack (j-major, r9 layout), idx ----------------
// BgT layout [4 groups][256 j][352 k] fp16.
//  k 0..95 = x-part (w_ih cols, valid k<76), k 96..351 = h-part (w_hh cols, kh<252)
//  group 0=r, 1=z, 2=inn (h-part zero), 3=hn (x-part zero). j>=252 -> zero.
__global__ __launch_bounds__(256) void k_prep(
    const float* __restrict__ w_ih, const float* __restrict__ w_hh,
    const float* __restrict__ b_ih, const float* __restrict__ b_hh,
    const int* __restrict__ slen,
    const float* __restrict__ wq, const float* __restrict__ wk,
    const float* __restrict__ gcn_w,
    f16* __restrict__ BgT, f16* __restrict__ wq16, f16* __restrict__ wk16,
    f16* __restrict__ gw16, float* __restrict__ biasc, int* __restrict__ idx)
{
  int id = blockIdx.x*256 + threadIdx.x;
  if (id < 360448){ // BgT: (g*256+j)*352+k
    int g = id / (256*352); int rem = id % (256*352);
    int j = rem / 352; int k = rem % 352;
    float v = 0.f;
    if (j < 252){
      if (k < 96){
        if (k < 76 && g != 3){
          int row = (g==2) ? (504+j) : (g*252+j);
          v = w_ih[row*76 + k];
        }
      } else {
        int kh = k - 96;
        if (kh < 252 && g != 2){
          int row = (g==3) ? (504+j) : (g*252+j);
          v = w_hh[row*252 + kh];
        }
      }
    }
    BgT[id] = (f16)v;
    return;
  }
  id -= 360448;
  if (id < 65536){ wq16[id] = (f16)wq[id]; return; }
  id -= 65536;
  if (id < 65536){ wk16[id] = (f16)wk[id]; return; }
  id -= 65536;
  if (id < 65536){ int j = id >> 8, d = id & 255; gw16[id] = (f16)gcn_w[d*256 + j]; return; }
  id -= 65536;
  if (id < 1008){
    int g = id / 252, j = id % 252; float v;
    if (g==0) v = b_ih[j] + b_hh[j];
    else if (g==1) v = b_ih[252+j] + b_hh[252+j];
    else if (g==2) v = b_ih[504+j];
    else v = b_hh[504+j];
    biasc[id] = v; return;
  }
  id -= 1008;
  if (id < 4096){
    int s = slen[id] - 1; s = s < 0 ? 0 : (s > 47 ? 47 : s);
    idx[id] = s; return;
  }
}

// ---------------- x transpose+convert: x16t[t][n][96] fp16, k>=76 zero ----------------
__global__ __launch_bounds__(256) void k_xt(const float* __restrict__ x,
    f16* __restrict__ x16t)
{
  int id = blockIdx.x*256 + threadIdx.x;   // 48*4096*12 total
  int c = id % 12; int rem = id / 12;
  int n = rem & 4095; int t = rem >> 12;
  const float* xp = x + ((size_t)n*48 + t)*76;
  f16x8 o;
  #pragma unroll
  for (int e = 0; e < 8; ++e){
    int k = c*8 + e;
    o[e] = (k < 76) ? (f16)xp[k] : (f16)0.f;
  }
  *(f16x8*)(x16t + ((size_t)t*4096 + n)*96 + c*8) = o;
}

// ---------------- GRU: persistent, block-local recurrence ----------------
// r15 minus the non-temporal loads (r15 lesson: nt on gfx950 sets
// no-allocate at L2 TOO -- FETCH 34->100MB, GRU 579->853us; the weight
// stream MUST use the normal cached path to keep BgT L2-resident).
// Config: r9 pinned 4-slot rotation for streamed fragments (plain loads) +
// 8 LDS-cached slots (u0:R/Z/I, u1:R/Z/I, u2:R/Z; stream 528->400KB/step) +
// single-buffered hbuf (barrier after reads, barrier after writes) +
// idx in registers. LDS 144.5KB, 1 block/CU, 16 waves.
__global__ __launch_bounds__(1024, 4) void k_gru_all(
    const f16* __restrict__ x16t, const f16* __restrict__ BgT,
    const float* __restrict__ biasc, const float* __restrict__ h0,
    const int* __restrict__ idxp, float* __restrict__ xstar,
    f16* __restrict__ xs16)
{
  __shared__ f16 hbuf[32][256];    // 16 KB (single buffer)
  __shared__ f16 wc[8][16][512];   // 128 KB: 8 cached weight slots
  int lane = threadIdx.x & 63, w = threadIdx.x >> 6;   // w: 0..15
  int l16 = lane & 15, lq = lane >> 4;
  int nb = blockIdx.x * 32;

  for (int i = threadIdx.x; i < 32*256; i += 1024){
    int row = i >> 8, c = i & 255;
    int sc = (((c >> 3) ^ (row & 7)) << 3) | (c & 7);
    hbuf[row][sc] = (c < 252) ? (f16)h0[c] : (f16)0.f;
  }

  int j = w*16 + l16;
  bool jv = (j < 252);
  int js = jv ? j : 251;
  float bR = biasc[js], bZ = biasc[252+js], bI = biasc[504+js], bH = biasc[756+js];
  const f16* pR = BgT + (size_t)(0*256 + j)*352 + lq*8;
  const f16* pZ = BgT + (size_t)(1*256 + j)*352 + lq*8;
  const f16* pI = BgT + (size_t)(2*256 + j)*352 + lq*8;
  const f16* pH = BgT + (size_t)(3*256 + j)*352 + lq*8;
  const f16* xp0 = x16t + ((size_t)nb + l16)*96 + lq*8;        // + t*4096*96 + u*32
  const f16* xp1 = x16t + ((size_t)nb + 16 + l16)*96 + lq*8;

  // populate the persistent weight cache (once):
  // slots 0..2 = u0 R/Z/I, 3..5 = u1 R/Z/I, 6..7 = u2 R/Z
  *(f16x8*)&wc[0][w][lane*8] = *(const f16x8*)(pR);
  *(f16x8*)&wc[1][w][lane*8] = *(const f16x8*)(pZ);
  *(f16x8*)&wc[2][w][lane*8] = *(const f16x8*)(pI);
  *(f16x8*)&wc[3][w][lane*8] = *(const f16x8*)(pR + 32);
  *(f16x8*)&wc[4][w][lane*8] = *(const f16x8*)(pZ + 32);
  *(f16x8*)&wc[5][w][lane*8] = *(const f16x8*)(pI + 32);
  *(f16x8*)&wc[6][w][lane*8] = *(const f16x8*)(pR + 64);
  *(f16x8*)&wc[7][w][lane*8] = *(const f16x8*)(pZ + 64);

  float hown[2][4];   // [mf][r]
  int idxr[2][4];
  #pragma unroll
  for (int mf = 0; mf < 2; ++mf)
  #pragma unroll
  for (int r = 0; r < 4; ++r){
    hown[mf][r] = jv ? h0[js] : 0.f;
    idxr[mf][r] = idxp[nb + mf*16 + lq*4 + r];
  }

  __syncthreads();

  for (int t = 0; t < 48; ++t){
    f32x4 z4 = {0.f,0.f,0.f,0.f};
    f32x4 aR[2] = {z4,z4}, aZ[2] = {z4,z4}, aI[2] = {z4,z4}, aH[2] = {z4,z4};
    size_t xt = (size_t)t*4096*96;

    // pinned 4-slot rotating pipeline over the STREAMED fragments
    // (u=2: I only; u=3..10: R,Z,M). Plain cached loads (NO nontemporal).
    f16x8 R0,Z0,M0, R1,Z1,M1, R2,Z2,M2, R3,Z3,M3;
#define PIN3(s) asm volatile("" :: "v"(*(const f32x4*)&R##s), \
                                   "v"(*(const f32x4*)&Z##s), \
                                   "v"(*(const f32x4*)&M##s))
#define PIN1(s) asm volatile("" :: "v"(*(const f32x4*)&M##s))
#define LW(s,u) do{ \
      R##s = *(const f16x8*)(pR + (u)*32); \
      Z##s = *(const f16x8*)(pZ + (u)*32); \
      M##s = *(const f16x8*)(pH + (u)*32); \
      PIN3(s); }while(0)
#define LW1(s) do{ \
      M##s = *(const f16x8*)(pI + 64); \
      PIN1(s); }while(0)
#define MM(u, wR_, wZ_, wM_, a0, a1) do{ \
      aR[0] = MFMA(a0, wR_, aR[0]);  aR[1] = MFMA(a1, wR_, aR[1]); \
      aZ[0] = MFMA(a0, wZ_, aZ[0]);  aZ[1] = MFMA(a1, wZ_, aZ[1]); \
      if ((u) < 3){ aI[0] = MFMA(a0, wM_, aI[0]);  aI[1] = MFMA(a1, wM_, aI[1]); } \
      else        { aH[0] = MFMA(a0, wM_, aH[0]);  aH[1] = MFMA(a1, wM_, aH[1]); } \
    }while(0)
#define STEP(s,u) do{ \
      int chunk = ((u) - 3)*4 + lq; \
      f16x8 a0 = *(const f16x8*)(&hbuf[l16][(chunk ^ (l16 & 7)) << 3]); \
      f16x8 a1 = *(const f16x8*)(&hbuf[16 + l16][(chunk ^ (l16 & 7)) << 3]); \
      MM(u, R##s, Z##s, M##s, a0, a1); \
    }while(0)
#define STEP_L(u) do{ \
      f16x8 wR_ = *(const f16x8*)&wc[(u)*3+0][w][lane*8]; \
      f16x8 wZ_ = *(const f16x8*)&wc[(u)*3+1][w][lane*8]; \
      f16x8 wM_ = *(const f16x8*)&wc[(u)*3+2][w][lane*8]; \
      f16x8 a0 = *(const f16x8*)(xp0 + xt + (u)*32); \
      f16x8 a1 = *(const f16x8*)(xp1 + xt + (u)*32); \
      MM(u, wR_, wZ_, wM_, a0, a1); \
    }while(0)
#define STEP2(s) do{ \
      f16x8 wR_ = *(const f16x8*)&wc[6][w][lane*8]; \
      f16x8 wZ_ = *(const f16x8*)&wc[7][w][lane*8]; \
      f16x8 a0 = *(const f16x8*)(xp0 + xt + 64); \
      f16x8 a1 = *(const f16x8*)(xp1 + xt + 64); \
      MM(2, wR_, wZ_, M##s, a0, a1); \
    }while(0)

    LW1(0); LW(1,3); LW(2,4); LW(3,5);
    STEP_L(0);
    STEP_L(1);
    STEP2(0);    LW(0,6);
    STEP(1,3);   LW(1,7);
    STEP(2,4);   LW(2,8);
    STEP(3,5);   LW(3,9);
    STEP(0,6);   LW(0,10);
    STEP(1,7);
    STEP(2,8);
    STEP(3,9);
    STEP(0,10);
#undef LW
#undef LW1
#undef STEP
#undef STEP_L
#undef STEP2
#undef MM
#undef PIN3
#undef PIN1

    __syncthreads();   // all h reads for step t complete

    // epilogue: gate math, write hbuf (swizzled) + xstar/xs16 on last valid step
    #pragma unroll
    for (int mf = 0; mf < 2; ++mf)
    #pragma unroll
    for (int r = 0; r < 4; ++r){
      int row = mf*16 + lq*4 + r;
      float rr = sigm(aR[mf][r] + bR);
      float zz = sigm(aZ[mf][r] + bZ);
      float ng = tanh_f(aI[mf][r] + bI + rr*(aH[mf][r] + bH));
      float hnew = (1.f - zz)*ng + zz*hown[mf][r];
      hnew = jv ? hnew : 0.f;
      hown[mf][r] = hnew;
      int sc = (((j >> 3) ^ (row & 7)) << 3) | (j & 7);
      hbuf[row][sc] = (f16)hnew;
      if (jv && idxr[mf][r] == t){
        xstar[((size_t)(nb + row) << 8) + j] = hnew;
        xs16[((size_t)(nb + row) << 8) + j] = (f16)hnew;
      }
    }
    __syncthreads();   // h writes visible before step t+1 reads
  }
}

// ---------------- demo cols of x_star (c 252..255), f32 + f16 ----------------
__global__ __launch_bounds__(256) void k_xdemo(const float* __restrict__ x_demo,
    float* __restrict__ xs32, f16* __restrict__ xs16)
{
  int id = blockIdx.x*256 + threadIdx.x;   // 4096*4
  int n = id >> 2, c = id & 3;
  float v = x_demo[id];
  xs32[((size_t)n << 8) + 252 + c] = v;
  xs16[((size_t)n << 8) + 252 + c] = (f16)v;
}

// ---------------- fused q+k projections (one launch) ----------------
__global__ __launch_bounds__(256) void k_projqk(const f16* __restrict__ xs16,
    const f16* __restrict__ wq16, const f16* __restrict__ wk16,
    const float* __restrict__ bq, const float* __restrict__ bk,
    const float* __restrict__ wo, f16* __restrict__ qf, f16* __restrict__ kf)
{
  int lane = threadIdx.x & 63, wv = threadIdx.x >> 6;
  int l16 = lane & 15, lq = lane >> 4;
  int nb = blockIdx.x * 64;
  int mode = blockIdx.y >> 2;           // 0: q, 1: k
  int yy = blockIdx.y & 3;
  const f16* w16 = mode ? wk16 : wq16;
  const float* bias = mode ? bk : bq;
  f16* out16 = mode ? kf : qf;
  int ocol = yy*64 + wv*16 + l16;
  f32x4 z4 = {0.f,0.f,0.f,0.f};
  f32x4 acc[4] = {z4,z4,z4,z4};
  #pragma unroll
  for (int ks = 0; ks < 8; ++ks){
    f16x8 b = *(const f16x8*)(w16 + (size_t)ocol*256 + ks*32 + lq*8);
    #pragma unroll
    for (int mi = 0; mi < 4; ++mi){
      f16x8 a = *(const f16x8*)(xs16 + (size_t)(nb + mi*16 + l16)*256 + ks*32 + lq*8);
      acc[mi] = MFMA(a, b, acc[mi]);
    }
  }
  float badd = bias[ocol];
  float scale = mode ? 1.f : wo[ocol >> 6]*0.125f;
  #pragma unroll
  for (int mi = 0; mi < 4; ++mi)
  #pragma unroll
  for (int r = 0; r < 4; ++r){
    int n = nb + mi*16 + lq*4 + r;
    float v = acc[mi][r] + badd;
    if (!mode) v *= scale;
    out16[(size_t)n*256 + ocol] = (f16)v;
  }
}

// ---------------- scores GEMM: 128x128 block tile, wave = 64x64 ----------------
__global__ __launch_bounds__(256) void k_scores(const f16* __restrict__ qf,
    const f16* __restrict__ kf, uint16_t* __restrict__ sco)
{
  int lane = threadIdx.x & 63, w = threadIdx.x >> 6;
  int l16 = lane & 15, lq = lane >> 4;
  int mh = w >> 1, jh = w & 1;
  int nb = blockIdx.x*128 + mh*64;
  int mb = blockIdx.y*128 + jh*64;
  f32x4 z4 = {0.f,0.f,0.f,0.f};
  f32x4 acc[4][4];
  #pragma unroll
  for (int i = 0; i < 4; ++i)
  #pragma unroll
  for (int j = 0; j < 4; ++j) acc[i][j] = z4;
  #pragma unroll
  for (int ks = 0; ks < 8; ++ks){
    f16x8 a[4], b[4];
    #pragma unroll
    for (int i = 0; i < 4; ++i){
      a[i] = *(const f16x8*)(qf + (size_t)(nb + i*16 + l16)*256 + ks*32 + lq*8);
      b[i] = *(const f16x8*)(kf + (size_t)(mb + i*16 + l16)*256 + ks*32 + lq*8);
    }
    #pragma unroll
    for (int mi = 0; mi < 4; ++mi)
    #pragma unroll
    for (int jf = 0; jf < 4; ++jf)
      acc[mi][jf] = MFMA(a[mi], b[jf], acc[mi][jf]);
  }
  #pragma unroll
  for (int mi = 0; mi < 4; ++mi)
  #pragma unroll
  for (int jf = 0; jf < 4; ++jf)
  #pragma unroll
  for (int r = 0; r < 4; ++r){
    int n = nb + mi*16 + lq*4 + r;
    int m = mb + jf*16 + l16;
    sco[((size_t)n << 12) + m] = f2bf(acc[mi][jf][r]);
  }
}

// ---------------- fused softmax stats + flags + degrees (block per row) ----------------
__global__ __launch_bounds__(256) void k_adj(const uint16_t* __restrict__ sco,
    const float* __restrict__ mask_edge, const float* __restrict__ phip,
    uint8_t* __restrict__ flags, float* __restrict__ sadj,
    float* __restrict__ dinv, float* __restrict__ dinva)
{
  int n = blockIdx.x;
  int lane = threadIdx.x & 63, wv = threadIdx.x >> 6;
  const uint16_t* row = sco + ((size_t)n << 12);
  int base = threadIdx.x * 16;
  const uint4* p = (const uint4*)(row + base);
  uint4 w0 = p[0], w1 = p[1];
  uint32_t ws_[8] = {w0.x,w0.y,w0.z,w0.w,w1.x,w1.y,w1.z,w1.w};
  float v[16];
  #pragma unroll
  for (int i = 0; i < 8; ++i){
    v[2*i]   = bf2f((uint16_t)(ws_[i] & 0xffffu));
    v[2*i+1] = bf2f((uint16_t)(ws_[i] >> 16));
  }
  float mx = v[0];
  #pragma unroll
  for (int i = 1; i < 16; ++i) mx = fmaxf(mx, v[i]);
  #pragma unroll
  for (int o = 32; o >= 1; o >>= 1) mx = fmaxf(mx, __shfl_xor(mx, o));
  __shared__ float redA[4], redB[4], redC[4], redD[4];
  if (lane == 0) redA[wv] = mx;
  __syncthreads();
  mx = fmaxf(fmaxf(redA[0], redA[1]), fmaxf(redA[2], redA[3]));
  float s = 0.f;
  #pragma unroll
  for (int i = 0; i < 16; ++i){ v[i] = __expf(v[i] - mx); s += v[i]; }
  #pragma unroll
  for (int o = 32; o >= 1; o >>= 1) s += __shfl_xor(s, o);
  if (lane == 0) redB[wv] = s;
  __syncthreads();
  float rs = 1.f / (redB[0] + redB[1] + redB[2] + redB[3]);
  float phi = phip[0];
  uint32_t by[16]; int c0 = 0, c1 = 0;
  #pragma unroll
  for (int e = 0; e < 16; ++e){
    float a = v[e] * rs;
    int col = base + e;
    uint32_t b = (a >= phi && col != n) ? 1u : 0u;
    if (b){ if (mask_edge[((size_t)n << 12) + col] >= 0.1f) b |= 2u; }
    by[e] = b;
    c0 += (int)(b & 1u);
    c1 += (int)(b >> 1);
  }
  uint4 pk;
  pk.x = by[0]  | (by[1]  << 8) | (by[2]  << 16) | (by[3]  << 24);
  pk.y = by[4]  | (by[5]  << 8) | (by[6]  << 16) | (by[7]  << 24);
  pk.z = by[8]  | (by[9]  << 8) | (by[10] << 16) | (by[11] << 24);
  pk.w = by[12] | (by[13] << 8) | (by[14] << 16) | (by[15] << 24);
  *(uint4*)(flags + ((size_t)n << 12) + base) = pk;
  float f0 = (float)c0, f1 = (float)c1;
  #pragma unroll
  for (int o = 32; o >= 1; o >>= 1){ f0 += __shfl_xor(f0, o); f1 += __shfl_xor(f1, o); }
  if (lane == 0){ redC[wv] = f0; redD[wv] = f1; }
  __syncthreads();
  if (threadIdx.x == 0){
    float d0 = redC[0]+redC[1]+redC[2]+redC[3];
    float d1 = redD[0]+redD[1]+redD[2]+redD[3];
    sadj[n] = d0;
    dinv[n]  = rsqrtf(1.f + d0);
    dinva[n] = rsqrtf(1.f + d1);
  }
}

// ---------------- xw = xs@gcn_w ; y = dinv*xw (fp16) ----------------
__global__ __launch_bounds__(256) void k_xw_y(const f16* __restrict__ xs16,
    const f16* __restrict__ gw16, const float* __restrict__ dinv,
    const float* __restrict__ dinva, f16* __restrict__ y16, f16* __restrict__ ya16)
{
  int lane = threadIdx.x & 63, wv = threadIdx.x >> 6;
  int l16 = lane & 15, lq = lane >> 4;
  int nb = blockIdx.x * 64;
  int jcol = blockIdx.y*64 + wv*16 + l16;
  f32x4 z4 = {0.f,0.f,0.f,0.f};
  f32x4 acc[4] = {z4,z4,z4,z4};
  #pragma unroll
  for (int ks = 0; ks < 8; ++ks){
    f16x8 b = *(const f16x8*)(gw16 + (size_t)jcol*256 + ks*32 + lq*8);
    #pragma unroll
    for (int mi = 0; mi < 4; ++mi){
      f16x8 a = *(const f16x8*)(xs16 + (size_t)(nb + mi*16 + l16)*256 + ks*32 + lq*8);
      acc[mi] = MFMA(a, b, acc[mi]);
    }
  }
  #pragma unroll
  for (int mi = 0; mi < 4; ++mi)
  #pragma unroll
  for (int r = 0; r < 4; ++r){
    int n = nb + mi*16 + lq*4 + r;
    float v = acc[mi][r];
    y16[(size_t)n*256 + jcol]  = (f16)(dinv[n]*v);
    ya16[(size_t)n*256 + jcol] = (f16)(dinva[n]*v);
  }
}

// ---------------- GCN gather: both variants in one block ----------------
__global__ __launch_bounds__(256) void k_zgather(const uint8_t* __restrict__ flags,
    const f16* __restrict__ y16, const f16* __restrict__ ya16,
    const float* __restrict__ dinv, const float* __restrict__ dinva,
    const float* __restrict__ gcn_b, float* __restrict__ z32, float* __restrict__ za32)
{
  int n = blockIdx.x;
  int lane = threadIdx.x & 63, wv = threadIdx.x >> 6;
  uint4 w = ((const uint4*)(flags + ((size_t)n << 12)))[threadIdx.x];
  uint32_t m0[4] = {w.x & 0x01010101u, w.y & 0x01010101u, w.z & 0x01010101u, w.w & 0x01010101u};
  uint32_t m1[4] = {w.x & 0x02020202u, w.y & 0x02020202u, w.z & 0x02020202u, w.w & 0x02020202u};
  int c0 = __popc(m0[0]) + __popc(m0[1]) + __popc(m0[2]) + __popc(m0[3]);
  int c1 = __popc(m1[0]) + __popc(m1[1]) + __popc(m1[2]) + __popc(m1[3]);
  int v0 = c0, v1 = c1;
  #pragma unroll
  for (int o = 1; o < 64; o <<= 1){
    int u0 = __shfl_up(v0, o), u1 = __shfl_up(v1, o);
    if (lane >= o){ v0 += u0; v1 += u1; }
  }
  __shared__ int wsum0[4], wsum1[4];
  if (lane == 63){ wsum0[wv] = v0; wsum1[wv] = v1; }
  __syncthreads();
  int pos0 = v0 - c0, pos1 = v1 - c1;
  #pragma unroll
  for (int i = 0; i < 4; ++i) if (i < wv){ pos0 += wsum0[i]; pos1 += wsum1[i]; }
  int tot0 = wsum0[0]+wsum0[1]+wsum0[2]+wsum0[3];
  int tot1 = wsum1[0]+wsum1[1]+wsum1[2]+wsum1[3];
  __shared__ uint16_t list0[4096];
  __shared__ uint16_t list1[4096];
  int cbase = threadIdx.x * 16;
  #pragma unroll
  for (int q = 0; q < 4; ++q){
    uint32_t m = m0[q];
    while (m){
      int b = __ffs(m) - 1;
      list0[pos0++] = (uint16_t)(cbase + q*4 + (b >> 3));
      m &= m - 1;
    }
    m = m1[q];
    while (m){
      int b = __ffs(m) - 1;
      list1[pos1++] = (uint16_t)(cbase + q*4 + (b >> 3));
      m &= m - 1;
    }
  }
  __syncthreads();
  int j = threadIdx.x;
  float acc0 = (float)y16[((size_t)n << 8) + j];
  float acc1 = (float)ya16[((size_t)n << 8) + j];
  for (int i = 0; i < tot0; ++i) acc0 += (float)y16[((size_t)list0[i] << 8) + j];
  for (int i = 0; i < tot1; ++i) acc1 += (float)ya16[((size_t)list1[i] << 8) + j];
  z32[((size_t)n << 8) + j]  = dinv[n]*acc0 + gcn_b[j];
  za32[((size_t)n << 8) + j] = dinva[n]*acc1 + gcn_b[j];
}

// ---------------- clustering: qsoft, labels, colsum ----------------
__global__ __launch_bounds__(256) void k_cluster(const float* __restrict__ xs32,
    const float* __restrict__ centers, float* __restrict__ qsoft,
    int* __restrict__ labels, float* __restrict__ colsum)
{
  int nb = blockIdx.x * 16;
  __shared__ float xs[16][256];
  __shared__ float ct[2560];   // transposed [d][k]
  __shared__ float d2s[16][10];
  __shared__ float qs[16][10];
  for (int i = threadIdx.x; i < 16*256; i += 256) xs[i >> 8][i & 255] = xs32[(size_t)nb*256 + i];
  for (int i = threadIdx.x; i < 2560; i += 256){ int k = i >> 8, d = i & 255; ct[d*10 + k] = centers[i]; }
  __syncthreads();
  if (threadIdx.x < 160){
    int r = threadIdx.x / 10, k = threadIdx.x % 10;
    float s = 0.f;
    for (int d = 0; d < 256; ++d){ float df = xs[r][d] - ct[d*10 + k]; s += df*df; }
    d2s[r][k] = s;
  }
  __syncthreads();
  if (threadIdx.x < 16){
    int r = threadIdx.x;
    float un[10]; float tot = 0.f;
    #pragma unroll
    for (int k = 0; k < 10; ++k){ un[k] = 1.f/(1.f + d2s[r][k]); tot += un[k]; }
    float inv = 1.f / tot;
    int best = 0; float bm = un[0];
    #pragma unroll
    for (int k = 1; k < 10; ++k){ if (un[k] > bm){ bm = un[k]; best = k; } }
    labels[nb + r] = best;
    #pragma unroll
    for (int k = 0; k < 10; ++k){ float q = un[k]*inv; qs[r][k] = q; qsoft[(size_t)(nb + r)*10 + k] = q; }
  }
  __syncthreads();
  if (threadIdx.x < 10){
    int k = threadIdx.x; float s = 0.f;
    #pragma unroll
    for (int r = 0; r < 16; ++r) s += qs[r][k];
    atomicAdd(&colsum[k], s);
  }
}

// ---------------- KL loss ----------------
__global__ __launch_bounds__(256) void k_kl(const float* __restrict__ qsoft,
    const float* __restrict__ colsum, float* __restrict__ klsum)
{
  int n = blockIdx.x*256 + threadIdx.x;
  float p[10]; float s = 0.f;
  #pragma unroll
  for (int k = 0; k < 10; ++k){
    float q = qsoft[(size_t)n*10 + k];
    float pu = q*q/colsum[k];
    p[k] = pu; s += pu;
  }
  float inv = 1.f/s; float kl = 0.f;
  #pragma unroll
  for (int k = 0; k < 10; ++k){
    float pk = p[k]*inv;
    float q = qsoft[(size_t)n*10 + k];
    kl += pk*__logf(pk/(q + 1e-6f));
  }
  int lane = threadIdx.x & 63, wv = threadIdx.x >> 6;
  #pragma unroll
  for (int o = 32; o >= 1; o >>= 1) kl += __shfl_xor(kl, o);
  __shared__ float red[4];
  if (lane == 0) red[wv] = kl;
  __syncthreads();
  if (threadIdx.x == 0) atomicAdd(klsum, red[0]+red[1]+red[2]+red[3]);
}

// ---------------- FFN + l2-normalize ----------------
__global__ __launch_bounds__(128) void k_ffn(const float* __restrict__ z32,
    const float* __restrict__ za32, const float* __restrict__ ffn_w,
    const float* __restrict__ ffn_b, f16* __restrict__ zn16, f16* __restrict__ zan16)
{
  int n = blockIdx.x; int aug = blockIdx.y;
  const float* z = (aug ? za32 : z32) + ((size_t)n << 8);
  __shared__ float zr[256];
  zr[threadIdx.x] = z[threadIdx.x];
  zr[threadIdx.x + 128] = z[threadIdx.x + 128];
  __syncthreads();
  int j = threadIdx.x;
  float acc = ffn_b[j];
  #pragma unroll 8
  for (int d = 0; d < 256; ++d) acc += zr[d]*ffn_w[d*128 + j];
  float ss = acc*acc;
  int lane = threadIdx.x & 63, wv = threadIdx.x >> 6;
  #pragma unroll
  for (int o = 32; o >= 1; o >>= 1) ss += __shfl_xor(ss, o);
  __shared__ float sred[2];
  if (lane == 0) sred[wv] = ss;
  __syncthreads();
  float tot = sred[0] + sred[1];
  float rn = 1.f / fmaxf(sqrtf(tot), 1e-12f);
  (aug ? zan16 : zn16)[((size_t)n << 7) + j] = (f16)(acc*rn);
}

// ---------------- contrastive loss partial sums ----------------
__global__ __launch_bounds__(256) void k_closs(const f16* __restrict__ zn,
    const f16* __restrict__ zan, const uint8_t* __restrict__ flags,
    const int* __restrict__ labels,
    float* __restrict__ rs1, float* __restrict__ rs2, float* __restrict__ rsA,
    float* __restrict__ rsC, float* __restrict__ rcC, float* __restrict__ rdI,
    float* __restrict__ rdi)
{
  int lane = threadIdx.x & 63;
  int ji = threadIdx.x >> 6;
  int l16 = lane & 15, lq = lane >> 4;
  int nb = blockIdx.x * 32;
  int mstart = blockIdx.y * 512;
  f16x8 A[2][4];
  #pragma unroll
  for (int mi = 0; mi < 2; ++mi)
  #pragma unroll
  for (int ks = 0; ks < 4; ++ks)
    A[mi][ks] = *(const f16x8*)(zn + (size_t)(nb + mi*16 + l16)*128 + ks*32 + lq*8);
  int labn[8];
  #pragma unroll
  for (int i = 0; i < 8; ++i) labn[i] = labels[nb + (i >> 2)*16 + lq*4 + (i & 3)];
  float a1[8]={}, a2[8]={}, aA[8]={}, aC[8]={}, aCc[8]={}, adI[8]={}, adi[8]={};
  uint8_t fA[8]; int labA;
  {
    int mcol0 = mstart + ji*16 + l16;
    #pragma unroll
    for (int i = 0; i < 8; ++i){
      int n = nb + (i >> 2)*16 + lq*4 + (i & 3);
      fA[i] = flags[((size_t)n << 12) + mcol0];
    }
    labA = labels[mcol0];
  }
  #pragma unroll
  for (int tile = 0; tile < 8; ++tile){
    int mcol = mstart + tile*64 + ji*16 + l16;
    uint8_t fB[8]; int labB = 0;
    if (tile < 7){
      int mn = mcol + 64;
      #pragma unroll
      for (int i = 0; i < 8; ++i){
        int n = nb + (i >> 2)*16 + lq*4 + (i & 3);
        fB[i] = flags[((size_t)n << 12) + mn];
      }
      labB = labels[mn];
    }
    f32x4 z4 = {0.f,0.f,0.f,0.f};
    f32x4 acc1[2] = {z4, z4};
    f32x4 acc2[2] = {z4, z4};
    #pragma unroll
    for (int ks = 0; ks < 4; ++ks){
      f16x8 b1 = *(const f16x8*)(zn  + (size_t)mcol*128 + ks*32 + lq*8);
      f16x8 b2 = *(const f16x8*)(zan + (size_t)mcol*128 + ks*32 + lq*8);
      #pragma unroll
      for (int mi = 0; mi < 2; ++mi){
        acc1[mi] = MFMA(A[mi][ks], b1, acc1[mi]);
        acc2[mi] = MFMA(A[mi][ks], b2, acc2[mi]);
      }
    }
    #pragma unroll
    for (int mi = 0; mi < 2; ++mi)
    #pragma unroll
    for (int r = 0; r < 4; ++r){
      int i8 = mi*4 + r;
      int n = nb + mi*16 + lq*4 + r;
      float e1 = __expf(2.f*acc1[mi][r]);
      float e2 = __expf(2.f*acc2[mi][r]);
      uint8_t fl = fA[i8];
      a1[i8] += e1; a2[i8] += e2;
      bool adjb = (fl & 1);
      if (adjb) aA[i8] += e1;
      if (!adjb && labn[i8] == labA && n != mcol){ aC[i8] += e1; aCc[i8] += 1.f; }
      if (n == mcol){ adI[i8] += e2; adi[i8] += e1; }
    }
    if (tile < 7){
      #pragma unroll
      for (int i = 0; i < 8; ++i) fA[i] = fB[i];
      labA = labB;
    }
  }
  #pragma unroll
  for (int i = 0; i < 8; ++i){
    #pragma unroll
    for (int o = 1; o < 16; o <<= 1){
      a1[i]  += __shfl_xor(a1[i], o);  a2[i]  += __shfl_xor(a2[i], o);
      aA[i]  += __shfl_xor(aA[i], o);  aC[i]  += __shfl_xor(aC[i], o);
      aCc[i] += __shfl_xor(aCc[i], o); adI[i] += __shfl_xor(adI[i], o);
      adi[i] += __shfl_xor(adi[i], o);
    }
  }
  if (l16 == 0){
    #pragma unroll
    for (int i = 0; i < 8; ++i){
      int n = nb + (i >> 2)*16 + lq*4 + (i & 3);
      atomicAdd(&rs1[n], a1[i]);  atomicAdd(&rs2[n], a2[i]);
      atomicAdd(&rsA[n], aA[i]);  atomicAdd(&rsC[n], aC[i]);
      atomicAdd(&rcC[n], aCc[i]); atomicAdd(&rdI[n], adI[i]);
      atomicAdd(&rdi[n], adi[i]);
    }
  }
}

// ---------------- contrastive loss finalize ----------------
__global__ __launch_bounds__(256) void k_clfinal(const float* __restrict__ rs1,
    const float* __restrict__ rs2, const float* __restrict__ rsA,
    const float* __restrict__ rsC, const float* __restrict__ rcC,
    const float* __restrict__ rdI, const float* __restrict__ rdi,
    const float* __restrict__ sadj, float* __restrict__ clsum)
{
  int n = blockIdx.x*256 + threadIdx.x;
  float pos = rdI[n] + rsA[n] + rsC[n];
  float den = rs1[n] + rs2[n] - rdi[n];
  float cnt = sadj[n] + rcC[n] + 1.f;
  float v = __logf(pos/den)/cnt;
  int lane = threadIdx.x & 63, wv = threadIdx.x >> 6;
  #pragma unroll
  for (int o = 32; o >= 1; o >>= 1) v += __shfl_xor(v, o);
  __shared__ float red[4];
  if (lane == 0) red[wv] = v;
  __syncthreads();
  if (threadIdx.x == 0) atomicAdd(clsum, red[0]+red[1]+red[2]+red[3]);
}

__global__ void k_loss(const float* __restrict__ scal, float* __restrict__ out){
  out[8192] = scal[0]*(1.f/4096.f) - scal[1];
}

// ---------------- output head (wave per row) ----------------
__global__ __launch_bounds__(256) void k_outhead(const float* __restrict__ z32,
    const float* __restrict__ pre_w, const float* __restrict__ pre_b,
    float* __restrict__ out)
{
  int lane = threadIdx.x & 63, wv = threadIdx.x >> 6;
  int n = blockIdx.x*4 + wv;
  float4 zv = *(const float4*)(z32 + ((size_t)n << 8) + lane*4);
  float4 w0 = *(const float4*)(pre_w + lane*8);
  float4 w1 = *(const float4*)(pre_w + lane*8 + 4);
  float c0 = zv.x*w0.x + zv.y*w0.z + zv.z*w1.x + zv.w*w1.z;
  float c1 = zv.x*w0.y + zv.y*w0.w + zv.z*w1.y + zv.w*w1.w;
  #pragma unroll
  for (int o = 32; o >= 1; o >>= 1){ c0 += __shfl_xor(c0, o); c1 += __shfl_xor(c1, o); }
  if (lane == 0){
    out[(size_t)n*2]     = c0 + pre_b[0];
    out[(size_t)n*2 + 1] = c1 + pre_b[1];
  }
}

// ---------------- host launch ----------------
extern "C" void kernel_launch(void* const* d_in, const int* in_sizes, int n_in,
                              void* d_out, int out_size, void* d_ws, size_t ws_size,
                              hipStream_t stream)
{
  const float* x         = (const float*)d_in[0];
  const float* x_demo    = (const float*)d_in[1];
  const int*   slen      = (const int*)d_in[2];
  const float* mask_edge = (const float*)d_in[3];
  const float* w_ih      = (const float*)d_in[4];
  const float* w_hh      = (const float*)d_in[5];
  const float* b_ih      = (const float*)d_in[6];
  const float* b_hh      = (const float*)d_in[7];
  const float* h0        = (const float*)d_in[8];
  const float* wq        = (const float*)d_in[9];
  const float* bq        = (const float*)d_in[10];
  const float* wk        = (const float*)d_in[11];
  const float* bk        = (const float*)d_in[12];
  const float* wo        = (const float*)d_in[13];
  const float* phi       = (const float*)d_in[15];
  const float* centers   = (const float*)d_in[16];
  const float* gcn_w     = (const float*)d_in[17];
  const float* gcn_b     = (const float*)d_in[18];
  const float* ffn_w     = (const float*)d_in[19];
  const float* ffn_b     = (const float*)d_in[20];
  const float* pre_w     = (const float*)d_in[21];
  const float* pre_b     = (const float*)d_in[22];
  float* out = (float*)d_out;

  size_t off = 0;
  char* base = (char*)d_ws;
  auto take = [&](size_t bytes)->void*{
    void* p = base + off;
    off += (bytes + 255) & ~(size_t)255;
    return p;
  };
  f16*   BgT    = (f16*)take((size_t)4*256*352*2);
  f16*   wq16   = (f16*)take((size_t)65536*2);
  f16*   wk16   = (f16*)take((size_t)65536*2);
  f16*   gw16   = (f16*)take((size_t)65536*2);
  float* biasc  = (float*)take(1008*4);
  int*   idx    = (int*)take(4096*4);
  float* xs32   = (float*)take((size_t)4096*256*4);
  f16*   xs16   = (f16*)take((size_t)4096*256*2);
  f16*   qf16   = (f16*)take((size_t)4096*256*2);
  f16*   kf16   = (f16*)take((size_t)4096*256*2);
  uint16_t* sco = (uint16_t*)take((size_t)4096*4096*2);
  uint8_t* flags= (uint8_t*)take((size_t)4096*4096);
  float* sadj   = (float*)take(4096*4);
  float* dinv   = (float*)take(4096*4);
  float* dinva  = (float*)take(4096*4);
  f16*   y16    = (f16*)take((size_t)4096*256*2);
  f16*   ya16   = (f16*)take((size_t)4096*256*2);
  float* z32    = (float*)take((size_t)4096*256*4);
  float* za32   = (float*)take((size_t)4096*256*4);
  f16*   zn16   = (f16*)take((size_t)4096*128*2);
  f16*   zan16  = (f16*)take((size_t)4096*128*2);
  float* qsoft  = (float*)take((size_t)4096*10*4);
  int*   labels = (int*)take(4096*4);
  float* colsum = (float*)take(64);
  float* scal   = (float*)take(64);         // [0]=klsum, [1]=clsum
  float* rsbuf  = (float*)take((size_t)7*4096*4);
  float* rs1 = rsbuf,        *rs2 = rsbuf + 4096, *rsA = rsbuf + 2*4096;
  float* rsC = rsbuf + 3*4096, *rcC = rsbuf + 4*4096;
  float* rdI = rsbuf + 5*4096, *rdi = rsbuf + 6*4096;

  // x16t[48][4096][96] fp16 (37.75 MB) aliases sco(33.55MB)+flags head:
  // x16t is only live during the GRU; sco/flags are written strictly after.
  f16* x16t = (f16*)sco;

  hipMemsetAsync(colsum, 0, 64, stream);
  hipMemsetAsync(scal, 0, 64, stream);
  hipMemsetAsync(rsbuf, 0, (size_t)7*4096*4, stream);

  k_prep<<<2196, 256, 0, stream>>>(w_ih, w_hh, b_ih, b_hh, slen, wq, wk, gcn_w,
                                   BgT, wq16, wk16, gw16, biasc, idx);
  k_xt<<<9216, 256, 0, stream>>>(x, x16t);
  k_xdemo<<<64, 256, 0, stream>>>(x_demo, xs32, xs16);
  k_gru_all<<<128, 1024, 0, stream>>>(x16t, BgT, biasc, h0, idx, xs32, xs16);
  k_projqk<<<dim3(64, 8), 256, 0, stream>>>(xs16, wq16, wk16, bq, bk, wo, qf16, kf16);
  k_scores<<<dim3(32, 32), 256, 0, stream>>>(qf16, kf16, sco);
  k_adj<<<4096, 256, 0, stream>>>(sco, mask_edge, phi, flags, sadj, dinv, dinva);
  k_xw_y<<<dim3(64, 4), 256, 0, stream>>>(xs16, gw16, dinv, dinva, y16, ya16);
  k_zgather<<<4096, 256, 0, stream>>>(flags, y16, ya16, dinv, dinva, gcn_b, z32, za32);
  k_cluster<<<256, 256, 0, stream>>>(xs32, centers, qsoft, labels, colsum);
  k_kl<<<16, 256, 0, stream>>>(qsoft, colsum, &scal[0]);
  k_ffn<<<dim3(4096, 2), 128, 0, stream>>>(z32, za32, ffn_w, ffn_b, zn16, zan16);
  k_closs<<<dim3(128, 8), 256, 0, stream>>>(zn16, zan16, flags, labels,
                                            rs1, rs2, rsA, rsC, rcC, rdI, rdi);
  k_clfinal<<<16, 256, 0, stream>>>(rs1, rs2, rsA, rsC, rcC, rdI, rdi, sadj, &scal[1]);
  k_loss<<<1, 1, 0, stream>>>(scal, out);
  k_outhead<<<1024, 256, 0, stream>>>(z32, pre_w, pre_b, out);

  (void)in_sizes; (void)n_in; (void)out_size; (void)ws_size;
}

// Round 17
// 799.604 us; speedup vs baseline: 1.3862x; 1.0302x over previous
//
#include <hip/hip_runtime.h>
#include <cstdint>
#include <cstddef>

// ---------------- types / helpers ----------------
typedef _Float16 f16;
typedef f16 f16x8 __attribute__((ext_vector_type(8)));
typedef float f32x4 __attribute__((ext_vector_type(4)));

#define MFMA(a,b,c) __builtin_amdgcn_mfma_f32_16x16x32_f16(a,b,c,0,0,0)

__device__ __forceinline__ float sigm(float x){ return 1.f/(1.f+__expf(-x)); }
__device__ __forceinline__ float tanh_f(float x){
  float a = __expf(-2.f*fabsf(x));
  float t = (1.f-a)/(1.f+a);
  return x >= 0.f ? t : -t;
}
__device__ __forceinline__ uint16_t f2bf(float f){
  uint32_t u = __float_as_uint(f);
  return (uint16_t)((u + 0x7fffu + ((u>>16)&1u)) >> 16);
}
__device__ __forceinline__ float bf2f(uint16_t h){
  return __uint_as_float(((uint32_t)h) << 16);
}

// ---------------- prep: weights repack (j-major, r9 layout), idx ----------------
// BgT layout [4 groups][256 j][352 k] fp16.
//  k 0..95 = x-part (w_ih cols, valid k<76), k 96..351 = h-part (w_hh cols, kh<252)
//  group 0=r, 1=z, 2=inn (h-part zero), 3=hn (x-part zero). j>=252 -> zero.
__global__ __launch_bounds__(256) void k_prep(
    const float* __restrict__ w_ih, const float* __restrict__ w_hh,
    const float* __restrict__ b_ih, const float* __restrict__ b_hh,
    const int* __restrict__ slen,
    const float* __restrict__ wq, const float* __restrict__ wk,
    const float* __restrict__ gcn_w,
    f16* __restrict__ BgT, f16* __restrict__ wq16, f16* __restrict__ wk16,
    f16* __restrict__ gw16, float* __restrict__ biasc, int* __restrict__ idx)
{
  int id = blockIdx.x*256 + threadIdx.x;
  if (id < 360448){ // BgT: (g*256+j)*352+k
    int g = id / (256*352); int rem = id % (256*352);
    int j = rem / 352; int k = rem % 352;
    float v = 0.f;
    if (j < 252){
      if (k < 96){
        if (k < 76 && g != 3){
          int row = (g==2) ? (504+j) : (g*252+j);
          v = w_ih[row*76 + k];
        }
      } else {
        int kh = k - 96;
        if (kh < 252 && g != 2){
          int row = (g==3) ? (504+j) : (g*252+j);
          v = w_hh[row*252 + kh];
        }
      }
    }
    BgT[id] = (f16)v;
    return;
  }
  id -= 360448;
  if (id < 65536){ wq16[id] = (f16)wq[id]; return; }
  id -= 65536;
  if (id < 65536){ wk16[id] = (f16)wk[id]; return; }
  id -= 65536;
  if (id < 65536){ int j = id >> 8, d = id & 255; gw16[id] = (f16)gcn_w[d*256 + j]; return; }
  id -= 65536;
  if (id < 1008){
    int g = id / 252, j = id % 252; float v;
    if (g==0) v = b_ih[j] + b_hh[j];
    else if (g==1) v = b_ih[252+j] + b_hh[252+j];
    else if (g==2) v = b_ih[504+j];
    else v = b_hh[504+j];
    biasc[id] = v; return;
  }
  id -= 1008;
  if (id < 4096){
    int s = slen[id] - 1; s = s < 0 ? 0 : (s > 47 ? 47 : s);
    idx[id] = s; return;
  }
}

// ---------------- x transpose+convert: x16t[t][n][96] fp16, k>=76 zero ----------------
__global__ __launch_bounds__(256) void k_xt(const float* __restrict__ x,
    f16* __restrict__ x16t)
{
  int id = blockIdx.x*256 + threadIdx.x;   // 48*4096*12 total
  int c = id % 12; int rem = id / 12;
  int n = rem & 4095; int t = rem >> 12;
  const float* xp = x + ((size_t)n*48 + t)*76;
  f16x8 o;
  #pragma unroll
  for (int e = 0; e < 8; ++e){
    int k = c*8 + e;
    o[e] = (k < 76) ? (f16)xp[k] : (f16)0.f;
  }
  *(f16x8*)(x16t + ((size_t)t*4096 + n)*96 + c*8) = o;
}

// ---------------- GRU: persistent, block-local recurrence ----------------
// RESTORED r14 config -- the best measured across 16 rounds (579us GRU,
// FETCH 34MB): r9 pinned 4-slot rotation for streamed fragments (plain
// cached loads; r15 lesson: nontemporal kills L2 residency) + 7 LDS-cached
// slots (u0:R/Z/I, u1:R/Z/I, u2:R; stream 528->416KB/step) + DOUBLE-buffered
// hbuf (ONE barrier/step; r16 lesson: single-buffer's 2nd barrier costs
// +0.9us/step, more than the 8th slot saves). LDS 144.5KB, 16 waves.
// Fitted cost model: t = 6.3us + 13.8ns/KB * streamed_KB = ~12us/step.
__global__ __launch_bounds__(1024, 4) void k_gru_all(
    const f16* __restrict__ x16t, const f16* __restrict__ BgT,
    const float* __restrict__ biasc, const float* __restrict__ h0,
    const int* __restrict__ idxp, float* __restrict__ xstar,
    f16* __restrict__ xs16)
{
  __shared__ f16 hbuf[2][32][256]; // 32 KB ping-pong
  __shared__ f16 wc[7][16][512];   // 112 KB: 7 cached weight slots
  __shared__ int idxl[32];
  int lane = threadIdx.x & 63, w = threadIdx.x >> 6;   // w: 0..15
  int l16 = lane & 15, lq = lane >> 4;
  int nb = blockIdx.x * 32;

  for (int i = threadIdx.x; i < 32*256; i += 1024){
    int row = i >> 8, c = i & 255;
    int sc = (((c >> 3) ^ (row & 7)) << 3) | (c & 7);
    hbuf[0][row][sc] = (c < 252) ? (f16)h0[c] : (f16)0.f;
  }
  if (threadIdx.x < 32) idxl[threadIdx.x] = idxp[nb + threadIdx.x];

  int j = w*16 + l16;
  bool jv = (j < 252);
  int js = jv ? j : 251;
  float bR = biasc[js], bZ = biasc[252+js], bI = biasc[504+js], bH = biasc[756+js];
  const f16* pR = BgT + (size_t)(0*256 + j)*352 + lq*8;
  const f16* pZ = BgT + (size_t)(1*256 + j)*352 + lq*8;
  const f16* pI = BgT + (size_t)(2*256 + j)*352 + lq*8;
  const f16* pH = BgT + (size_t)(3*256 + j)*352 + lq*8;
  const f16* xp0 = x16t + ((size_t)nb + l16)*96 + lq*8;        // + t*4096*96 + u*32
  const f16* xp1 = x16t + ((size_t)nb + 16 + l16)*96 + lq*8;

  // populate the persistent weight cache (once):
  // slots 0..2 = u0 R/Z/I, 3..5 = u1 R/Z/I, 6 = u2 R
  *(f16x8*)&wc[0][w][lane*8] = *(const f16x8*)(pR);
  *(f16x8*)&wc[1][w][lane*8] = *(const f16x8*)(pZ);
  *(f16x8*)&wc[2][w][lane*8] = *(const f16x8*)(pI);
  *(f16x8*)&wc[3][w][lane*8] = *(const f16x8*)(pR + 32);
  *(f16x8*)&wc[4][w][lane*8] = *(const f16x8*)(pZ + 32);
  *(f16x8*)&wc[5][w][lane*8] = *(const f16x8*)(pI + 32);
  *(f16x8*)&wc[6][w][lane*8] = *(const f16x8*)(pR + 64);

  float hown[2][4];   // [mf][r]
  #pragma unroll
  for (int mf = 0; mf < 2; ++mf)
  #pragma unroll
  for (int r = 0; r < 4; ++r)
    hown[mf][r] = jv ? h0[js] : 0.f;

  __syncthreads();

  for (int t = 0; t < 48; ++t){
    const f16 (*hin)[256] = hbuf[t & 1];
    f16 (*hout)[256]      = hbuf[(t & 1) ^ 1];
    f32x4 z4 = {0.f,0.f,0.f,0.f};
    f32x4 aR[2] = {z4,z4}, aZ[2] = {z4,z4}, aI[2] = {z4,z4}, aH[2] = {z4,z4};
    size_t xt = (size_t)t*4096*96;

    // pinned 4-slot rotating pipeline over the STREAMED fragments
    // (u=2: Z,M only; u=3..10: R,Z,M). Plain cached loads.
    f16x8 R0,Z0,M0, R1,Z1,M1, R2,Z2,M2, R3,Z3,M3;
#define PIN3(s) asm volatile("" :: "v"(*(const f32x4*)&R##s), \
                                   "v"(*(const f32x4*)&Z##s), \
                                   "v"(*(const f32x4*)&M##s))
#define PIN2(s) asm volatile("" :: "v"(*(const f32x4*)&Z##s), \
                                   "v"(*(const f32x4*)&M##s))
#define LW(s,u) do{ \
      R##s = *(const f16x8*)(pR + (u)*32); \
      Z##s = *(const f16x8*)(pZ + (u)*32); \
      M##s = *(const f16x8*)((((u) < 3) ? pI : pH) + (u)*32); \
      PIN3(s); }while(0)
#define LW2(s,u) do{ \
      Z##s = *(const f16x8*)(pZ + (u)*32); \
      M##s = *(const f16x8*)((((u) < 3) ? pI : pH) + (u)*32); \
      PIN2(s); }while(0)
#define MM(u, wR_, wZ_, wM_, a0, a1) do{ \
      aR[0] = MFMA(a0, wR_, aR[0]);  aR[1] = MFMA(a1, wR_, aR[1]); \
      aZ[0] = MFMA(a0, wZ_, aZ[0]);  aZ[1] = MFMA(a1, wZ_, aZ[1]); \
      if ((u) < 3){ aI[0] = MFMA(a0, wM_, aI[0]);  aI[1] = MFMA(a1, wM_, aI[1]); } \
      else        { aH[0] = MFMA(a0, wM_, aH[0]);  aH[1] = MFMA(a1, wM_, aH[1]); } \
    }while(0)
#define STEP(s,u) do{ \
      int chunk = ((u) - 3)*4 + lq; \
      f16x8 a0 = *(const f16x8*)(&hin[l16][(chunk ^ (l16 & 7)) << 3]); \
      f16x8 a1 = *(const f16x8*)(&hin[16 + l16][(chunk ^ (l16 & 7)) << 3]); \
      MM(u, R##s, Z##s, M##s, a0, a1); \
    }while(0)
#define STEP_L(u) do{ \
      f16x8 wR_ = *(const f16x8*)&wc[(u)*3+0][w][lane*8]; \
      f16x8 wZ_ = *(const f16x8*)&wc[(u)*3+1][w][lane*8]; \
      f16x8 wM_ = *(const f16x8*)&wc[(u)*3+2][w][lane*8]; \
      f16x8 a0 = *(const f16x8*)(xp0 + xt + (u)*32); \
      f16x8 a1 = *(const f16x8*)(xp1 + xt + (u)*32); \
      MM(u, wR_, wZ_, wM_, a0, a1); \
    }while(0)
#define STEP2(s) do{ \
      f16x8 wR_ = *(const f16x8*)&wc[6][w][lane*8]; \
      f16x8 a0 = *(const f16x8*)(xp0 + xt + 64); \
      f16x8 a1 = *(const f16x8*)(xp1 + xt + 64); \
      MM(2, wR_, Z##s, M##s, a0, a1); \
    }while(0)

    LW2(0,2); LW(1,3); LW(2,4); LW(3,5);
    STEP_L(0);
    STEP_L(1);
    STEP2(0);    LW(0,6);
    STEP(1,3);   LW(1,7);
    STEP(2,4);   LW(2,8);
    STEP(3,5);   LW(3,9);
    STEP(0,6);   LW(0,10);
    STEP(1,7);
    STEP(2,8);
    STEP(3,9);
    STEP(0,10);
#undef LW
#undef LW2
#undef STEP
#undef STEP_L
#undef STEP2
#undef MM
#undef PIN3
#undef PIN2

    // epilogue: gate math, write hout (swizzled) + xstar/xs16 on last valid step
    #pragma unroll
    for (int mf = 0; mf < 2; ++mf)
    #pragma unroll
    for (int r = 0; r < 4; ++r){
      int row = mf*16 + lq*4 + r;
      float rr = sigm(aR[mf][r] + bR);
      float zz = sigm(aZ[mf][r] + bZ);
      float ng = tanh_f(aI[mf][r] + bI + rr*(aH[mf][r] + bH));
      float hnew = (1.f - zz)*ng + zz*hown[mf][r];
      hnew = jv ? hnew : 0.f;
      hown[mf][r] = hnew;
      int sc = (((j >> 3) ^ (row & 7)) << 3) | (j & 7);
      hout[row][sc] = (f16)hnew;
      if (jv && idxl[row] == t){
        xstar[((size_t)(nb + row) << 8) + j] = hnew;
        xs16[((size_t)(nb + row) << 8) + j] = (f16)hnew;
      }
    }
    __syncthreads();
  }
}

// ---------------- demo cols of x_star (c 252..255), f32 + f16 ----------------
__global__ __launch_bounds__(256) void k_xdemo(const float* __restrict__ x_demo,
    float* __restrict__ xs32, f16* __restrict__ xs16)
{
  int id = blockIdx.x*256 + threadIdx.x;   // 4096*4
  int n = id >> 2, c = id & 3;
  float v = x_demo[id];
  xs32[((size_t)n << 8) + 252 + c] = v;
  xs16[((size_t)n << 8) + 252 + c] = (f16)v;
}

// ---------------- fused q+k projections (one launch) ----------------
__global__ __launch_bounds__(256) void k_projqk(const f16* __restrict__ xs16,
    const f16* __restrict__ wq16, const f16* __restrict__ wk16,
    const float* __restrict__ bq, const float* __restrict__ bk,
    const float* __restrict__ wo, f16* __restrict__ qf, f16* __restrict__ kf)
{
  int lane = threadIdx.x & 63, wv = threadIdx.x >> 6;
  int l16 = lane & 15, lq = lane >> 4;
  int nb = blockIdx.x * 64;
  int mode = blockIdx.y >> 2;           // 0: q, 1: k
  int yy = blockIdx.y & 3;
  const f16* w16 = mode ? wk16 : wq16;
  const float* bias = mode ? bk : bq;
  f16* out16 = mode ? kf : qf;
  int ocol = yy*64 + wv*16 + l16;
  f32x4 z4 = {0.f,0.f,0.f,0.f};
  f32x4 acc[4] = {z4,z4,z4,z4};
  #pragma unroll
  for (int ks = 0; ks < 8; ++ks){
    f16x8 b = *(const f16x8*)(w16 + (size_t)ocol*256 + ks*32 + lq*8);
    #pragma unroll
    for (int mi = 0; mi < 4; ++mi){
      f16x8 a = *(const f16x8*)(xs16 + (size_t)(nb + mi*16 + l16)*256 + ks*32 + lq*8);
      acc[mi] = MFMA(a, b, acc[mi]);
    }
  }
  float badd = bias[ocol];
  float scale = mode ? 1.f : wo[ocol >> 6]*0.125f;
  #pragma unroll
  for (int mi = 0; mi < 4; ++mi)
  #pragma unroll
  for (int r = 0; r < 4; ++r){
    int n = nb + mi*16 + lq*4 + r;
    float v = acc[mi][r] + badd;
    if (!mode) v *= scale;
    out16[(size_t)n*256 + ocol] = (f16)v;
  }
}

// ---------------- scores GEMM: 128x128 block tile, wave = 64x64 ----------------
__global__ __launch_bounds__(256) void k_scores(const f16* __restrict__ qf,
    const f16* __restrict__ kf, uint16_t* __restrict__ sco)
{
  int lane = threadIdx.x & 63, w = threadIdx.x >> 6;
  int l16 = lane & 15, lq = lane >> 4;
  int mh = w >> 1, jh = w & 1;
  int nb = blockIdx.x*128 + mh*64;
  int mb = blockIdx.y*128 + jh*64;
  f32x4 z4 = {0.f,0.f,0.f,0.f};
  f32x4 acc[4][4];
  #pragma unroll
  for (int i = 0; i < 4; ++i)
  #pragma unroll
  for (int j = 0; j < 4; ++j) acc[i][j] = z4;
  #pragma unroll
  for (int ks = 0; ks < 8; ++ks){
    f16x8 a[4], b[4];
    #pragma unroll
    for (int i = 0; i < 4; ++i){
      a[i] = *(const f16x8*)(qf + (size_t)(nb + i*16 + l16)*256 + ks*32 + lq*8);
      b[i] = *(const f16x8*)(kf + (size_t)(mb + i*16 + l16)*256 + ks*32 + lq*8);
    }
    #pragma unroll
    for (int mi = 0; mi < 4; ++mi)
    #pragma unroll
    for (int jf = 0; jf < 4; ++jf)
      acc[mi][jf] = MFMA(a[mi], b[jf], acc[mi][jf]);
  }
  #pragma unroll
  for (int mi = 0; mi < 4; ++mi)
  #pragma unroll
  for (int jf = 0; jf < 4; ++jf)
  #pragma unroll
  for (int r = 0; r < 4; ++r){
    int n = nb + mi*16 + lq*4 + r;
    int m = mb + jf*16 + l16;
    sco[((size_t)n << 12) + m] = f2bf(acc[mi][jf][r]);
  }
}

// ---------------- fused softmax stats + flags + degrees (block per row) ----------------
__global__ __launch_bounds__(256) void k_adj(const uint16_t* __restrict__ sco,
    const float* __restrict__ mask_edge, const float* __restrict__ phip,
    uint8_t* __restrict__ flags, float* __restrict__ sadj,
    float* __restrict__ dinv, float* __restrict__ dinva)
{
  int n = blockIdx.x;
  int lane = threadIdx.x & 63, wv = threadIdx.x >> 6;
  const uint16_t* row = sco + ((size_t)n << 12);
  int base = threadIdx.x * 16;
  const uint4* p = (const uint4*)(row + base);
  uint4 w0 = p[0], w1 = p[1];
  uint32_t ws_[8] = {w0.x,w0.y,w0.z,w0.w,w1.x,w1.y,w1.z,w1.w};
  float v[16];
  #pragma unroll
  for (int i = 0; i < 8; ++i){
    v[2*i]   = bf2f((uint16_t)(ws_[i] & 0xffffu));
    v[2*i+1] = bf2f((uint16_t)(ws_[i] >> 16));
  }
  float mx = v[0];
  #pragma unroll
  for (int i = 1; i < 16; ++i) mx = fmaxf(mx, v[i]);
  #pragma unroll
  for (int o = 32; o >= 1; o >>= 1) mx = fmaxf(mx, __shfl_xor(mx, o));
  __shared__ float redA[4], redB[4], redC[4], redD[4];
  if (lane == 0) redA[wv] = mx;
  __syncthreads();
  mx = fmaxf(fmaxf(redA[0], redA[1]), fmaxf(redA[2], redA[3]));
  float s = 0.f;
  #pragma unroll
  for (int i = 0; i < 16; ++i){ v[i] = __expf(v[i] - mx); s += v[i]; }
  #pragma unroll
  for (int o = 32; o >= 1; o >>= 1) s += __shfl_xor(s, o);
  if (lane == 0) redB[wv] = s;
  __syncthreads();
  float rs = 1.f / (redB[0] + redB[1] + redB[2] + redB[3]);
  float phi = phip[0];
  uint32_t by[16]; int c0 = 0, c1 = 0;
  #pragma unroll
  for (int e = 0; e < 16; ++e){
    float a = v[e] * rs;
    int col = base + e;
    uint32_t b = (a >= phi && col != n) ? 1u : 0u;
    if (b){ if (mask_edge[((size_t)n << 12) + col] >= 0.1f) b |= 2u; }
    by[e] = b;
    c0 += (int)(b & 1u);
    c1 += (int)(b >> 1);
  }
  uint4 pk;
  pk.x = by[0]  | (by[1]  << 8) | (by[2]  << 16) | (by[3]  << 24);
  pk.y = by[4]  | (by[5]  << 8) | (by[6]  << 16) | (by[7]  << 24);
  pk.z = by[8]  | (by[9]  << 8) | (by[10] << 16) | (by[11] << 24);
  pk.w = by[12] | (by[13] << 8) | (by[14] << 16) | (by[15] << 24);
  *(uint4*)(flags + ((size_t)n << 12) + base) = pk;
  float f0 = (float)c0, f1 = (float)c1;
  #pragma unroll
  for (int o = 32; o >= 1; o >>= 1){ f0 += __shfl_xor(f0, o); f1 += __shfl_xor(f1, o); }
  if (lane == 0){ redC[wv] = f0; redD[wv] = f1; }
  __syncthreads();
  if (threadIdx.x == 0){
    float d0 = redC[0]+redC[1]+redC[2]+redC[3];
    float d1 = redD[0]+redD[1]+redD[2]+redD[3];
    sadj[n] = d0;
    dinv[n]  = rsqrtf(1.f + d0);
    dinva[n] = rsqrtf(1.f + d1);
  }
}

// ---------------- xw = xs@gcn_w ; y = dinv*xw (fp16) ----------------
__global__ __launch_bounds__(256) void k_xw_y(const f16* __restrict__ xs16,
    const f16* __restrict__ gw16, const float* __restrict__ dinv,
    const float* __restrict__ dinva, f16* __restrict__ y16, f16* __restrict__ ya16)
{
  int lane = threadIdx.x & 63, wv = threadIdx.x >> 6;
  int l16 = lane & 15, lq = lane >> 4;
  int nb = blockIdx.x * 64;
  int jcol = blockIdx.y*64 + wv*16 + l16;
  f32x4 z4 = {0.f,0.f,0.f,0.f};
  f32x4 acc[4] = {z4,z4,z4,z4};
  #pragma unroll
  for (int ks = 0; ks < 8; ++ks){
    f16x8 b = *(const f16x8*)(gw16 + (size_t)jcol*256 + ks*32 + lq*8);
    #pragma unroll
    for (int mi = 0; mi < 4; ++mi){
      f16x8 a = *(const f16x8*)(xs16 + (size_t)(nb + mi*16 + l16)*256 + ks*32 + lq*8);
      acc[mi] = MFMA(a, b, acc[mi]);
    }
  }
  #pragma unroll
  for (int mi = 0; mi < 4; ++mi)
  #pragma unroll
  for (int r = 0; r < 4; ++r){
    int n = nb + mi*16 + lq*4 + r;
    float v = acc[mi][r];
    y16[(size_t)n*256 + jcol]  = (f16)(dinv[n]*v);
    ya16[(size_t)n*256 + jcol] = (f16)(dinva[n]*v);
  }
}

// ---------------- GCN gather: both variants in one block ----------------
__global__ __launch_bounds__(256) void k_zgather(const uint8_t* __restrict__ flags,
    const f16* __restrict__ y16, const f16* __restrict__ ya16,
    const float* __restrict__ dinv, const float* __restrict__ dinva,
    const float* __restrict__ gcn_b, float* __restrict__ z32, float* __restrict__ za32)
{
  int n = blockIdx.x;
  int lane = threadIdx.x & 63, wv = threadIdx.x >> 6;
  uint4 w = ((const uint4*)(flags + ((size_t)n << 12)))[threadIdx.x];
  uint32_t m0[4] = {w.x & 0x01010101u, w.y & 0x01010101u, w.z & 0x01010101u, w.w & 0x01010101u};
  uint32_t m1[4] = {w.x & 0x02020202u, w.y & 0x02020202u, w.z & 0x02020202u, w.w & 0x02020202u};
  int c0 = __popc(m0[0]) + __popc(m0[1]) + __popc(m0[2]) + __popc(m0[3]);
  int c1 = __popc(m1[0]) + __popc(m1[1]) + __popc(m1[2]) + __popc(m1[3]);
  int v0 = c0, v1 = c1;
  #pragma unroll
  for (int o = 1; o < 64; o <<= 1){
    int u0 = __shfl_up(v0, o), u1 = __shfl_up(v1, o);
    if (lane >= o){ v0 += u0; v1 += u1; }
  }
  __shared__ int wsum0[4], wsum1[4];
  if (lane == 63){ wsum0[wv] = v0; wsum1[wv] = v1; }
  __syncthreads();
  int pos0 = v0 - c0, pos1 = v1 - c1;
  #pragma unroll
  for (int i = 0; i < 4; ++i) if (i < wv){ pos0 += wsum0[i]; pos1 += wsum1[i]; }
  int tot0 = wsum0[0]+wsum0[1]+wsum0[2]+wsum0[3];
  int tot1 = wsum1[0]+wsum1[1]+wsum1[2]+wsum1[3];
  __shared__ uint16_t list0[4096];
  __shared__ uint16_t list1[4096];
  int cbase = threadIdx.x * 16;
  #pragma unroll
  for (int q = 0; q < 4; ++q){
    uint32_t m = m0[q];
    while (m){
      int b = __ffs(m) - 1;
      list0[pos0++] = (uint16_t)(cbase + q*4 + (b >> 3));
      m &= m - 1;
    }
    m = m1[q];
    while (m){
      int b = __ffs(m) - 1;
      list1[pos1++] = (uint16_t)(cbase + q*4 + (b >> 3));
      m &= m - 1;
    }
  }
  __syncthreads();
  int j = threadIdx.x;
  float acc0 = (float)y16[((size_t)n << 8) + j];
  float acc1 = (float)ya16[((size_t)n << 8) + j];
  for (int i = 0; i < tot0; ++i) acc0 += (float)y16[((size_t)list0[i] << 8) + j];
  for (int i = 0; i < tot1; ++i) acc1 += (float)ya16[((size_t)list1[i] << 8) + j];
  z32[((size_t)n << 8) + j]  = dinv[n]*acc0 + gcn_b[j];
  za32[((size_t)n << 8) + j] = dinva[n]*acc1 + gcn_b[j];
}

// ---------------- clustering: qsoft, labels, colsum ----------------
__global__ __launch_bounds__(256) void k_cluster(const float* __restrict__ xs32,
    const float* __restrict__ centers, float* __restrict__ qsoft,
    int* __restrict__ labels, float* __restrict__ colsum)
{
  int nb = blockIdx.x * 16;
  __shared__ float xs[16][256];
  __shared__ float ct[2560];   // transposed [d][k]
  __shared__ float d2s[16][10];
  __shared__ float qs[16][10];
  for (int i = threadIdx.x; i < 16*256; i += 256) xs[i >> 8][i & 255] = xs32[(size_t)nb*256 + i];
  for (int i = threadIdx.x; i < 2560; i += 256){ int k = i >> 8, d = i & 255; ct[d*10 + k] = centers[i]; }
  __syncthreads();
  if (threadIdx.x < 160){
    int r = threadIdx.x / 10, k = threadIdx.x % 10;
    float s = 0.f;
    for (int d = 0; d < 256; ++d){ float df = xs[r][d] - ct[d*10 + k]; s += df*df; }
    d2s[r][k] = s;
  }
  __syncthreads();
  if (threadIdx.x < 16){
    int r = threadIdx.x;
    float un[10]; float tot = 0.f;
    #pragma unroll
    for (int k = 0; k < 10; ++k){ un[k] = 1.f/(1.f + d2s[r][k]); tot += un[k]; }
    float inv = 1.f / tot;
    int best = 0; float bm = un[0];
    #pragma unroll
    for (int k = 1; k < 10; ++k){ if (un[k] > bm){ bm = un[k]; best = k; } }
    labels[nb + r] = best;
    #pragma unroll
    for (int k = 0; k < 10; ++k){ float q = un[k]*inv; qs[r][k] = q; qsoft[(size_t)(nb + r)*10 + k] = q; }
  }
  __syncthreads();
  if (threadIdx.x < 10){
    int k = threadIdx.x; float s = 0.f;
    #pragma unroll
    for (int r = 0; r < 16; ++r) s += qs[r][k];
    atomicAdd(&colsum[k], s);
  }
}

// ---------------- KL loss ----------------
__global__ __launch_bounds__(256) void k_kl(const float* __restrict__ qsoft,
    const float* __restrict__ colsum, float* __restrict__ klsum)
{
  int n = blockIdx.x*256 + threadIdx.x;
  float p[10]; float s = 0.f;
  #pragma unroll
  for (int k = 0; k < 10; ++k){
    float q = qsoft[(size_t)n*10 + k];
    float pu = q*q/colsum[k];
    p[k] = pu; s += pu;
  }
  float inv = 1.f/s; float kl = 0.f;
  #pragma unroll
  for (int k = 0; k < 10; ++k){
    float pk = p[k]*inv;
    float q = qsoft[(size_t)n*10 + k];
    kl += pk*__logf(pk/(q + 1e-6f));
  }
  int lane = threadIdx.x & 63, wv = threadIdx.x >> 6;
  #pragma unroll
  for (int o = 32; o >= 1; o >>= 1) kl += __shfl_xor(kl, o);
  __shared__ float red[4];
  if (lane == 0) red[wv] = kl;
  __syncthreads();
  if (threadIdx.x == 0) atomicAdd(klsum, red[0]+red[1]+red[2]+red[3]);
}

// ---------------- FFN + l2-normalize ----------------
__global__ __launch_bounds__(128) void k_ffn(const float* __restrict__ z32,
    const float* __restrict__ za32, const float* __restrict__ ffn_w,
    const float* __restrict__ ffn_b, f16* __restrict__ zn16, f16* __restrict__ zan16)
{
  int n = blockIdx.x; int aug = blockIdx.y;
  const float* z = (aug ? za32 : z32) + ((size_t)n << 8);
  __shared__ float zr[256];
  zr[threadIdx.x] = z[threadIdx.x];
  zr[threadIdx.x + 128] = z[threadIdx.x + 128];
  __syncthreads();
  int j = threadIdx.x;
  float acc = ffn_b[j];
  #pragma unroll 8
  for (int d = 0; d < 256; ++d) acc += zr[d]*ffn_w[d*128 + j];
  float ss = acc*acc;
  int lane = threadIdx.x & 63, wv = threadIdx.x >> 6;
  #pragma unroll
  for (int o = 32; o >= 1; o >>= 1) ss += __shfl_xor(ss, o);
  __shared__ float sred[2];
  if (lane == 0) sred[wv] = ss;
  __syncthreads();
  float tot = sred[0] + sred[1];
  float rn = 1.f / fmaxf(sqrtf(tot), 1e-12f);
  (aug ? zan16 : zn16)[((size_t)n << 7) + j] = (f16)(acc*rn);
}

// ---------------- contrastive loss partial sums ----------------
__global__ __launch_bounds__(256) void k_closs(const f16* __restrict__ zn,
    const f16* __restrict__ zan, const uint8_t* __restrict__ flags,
    const int* __restrict__ labels,
    float* __restrict__ rs1, float* __restrict__ rs2, float* __restrict__ rsA,
    float* __restrict__ rsC, float* __restrict__ rcC, float* __restrict__ rdI,
    float* __restrict__ rdi)
{
  int lane = threadIdx.x & 63;
  int ji = threadIdx.x >> 6;
  int l16 = lane & 15, lq = lane >> 4;
  int nb = blockIdx.x * 32;
  int mstart = blockIdx.y * 512;
  f16x8 A[2][4];
  #pragma unroll
  for (int mi = 0; mi < 2; ++mi)
  #pragma unroll
  for (int ks = 0; ks < 4; ++ks)
    A[mi][ks] = *(const f16x8*)(zn + (size_t)(nb + mi*16 + l16)*128 + ks*32 + lq*8);
  int labn[8];
  #pragma unroll
  for (int i = 0; i < 8; ++i) labn[i] = labels[nb + (i >> 2)*16 + lq*4 + (i & 3)];
  float a1[8]={}, a2[8]={}, aA[8]={}, aC[8]={}, aCc[8]={}, adI[8]={}, adi[8]={};
  uint8_t fA[8]; int labA;
  {
    int mcol0 = mstart + ji*16 + l16;
    #pragma unroll
    for (int i = 0; i < 8; ++i){
      int n = nb + (i >> 2)*16 + lq*4 + (i & 3);
      fA[i] = flags[((size_t)n << 12) + mcol0];
    }
    labA = labels[mcol0];
  }
  #pragma unroll
  for (int tile = 0; tile < 8; ++tile){
    int mcol = mstart + tile*64 + ji*16 + l16;
    uint8_t fB[8]; int labB = 0;
    if (tile < 7){
      int mn = mcol + 64;
      #pragma unroll
      for (int i = 0; i < 8; ++i){
        int n = nb + (i >> 2)*16 + lq*4 + (i & 3);
        fB[i] = flags[((size_t)n << 12) + mn];
      }
      labB = labels[mn];
    }
    f32x4 z4 = {0.f,0.f,0.f,0.f};
    f32x4 acc1[2] = {z4, z4};
    f32x4 acc2[2] = {z4, z4};
    #pragma unroll
    for (int ks = 0; ks < 4; ++ks){
      f16x8 b1 = *(const f16x8*)(zn  + (size_t)mcol*128 + ks*32 + lq*8);
      f16x8 b2 = *(const f16x8*)(zan + (size_t)mcol*128 + ks*32 + lq*8);
      #pragma unroll
      for (int mi = 0; mi < 2; ++mi){
        acc1[mi] = MFMA(A[mi][ks], b1, acc1[mi]);
        acc2[mi] = MFMA(A[mi][ks], b2, acc2[mi]);
      }
    }
    #pragma unroll
    for (int mi = 0; mi < 2; ++mi)
    #pragma unroll
    for (int r = 0; r < 4; ++r){
      int i8 = mi*4 + r;
      int n = nb + mi*16 + lq*4 + r;
      float e1 = __expf(2.f*acc1[mi][r]);
      float e2 = __expf(2.f*acc2[mi][r]);
      uint8_t fl = fA[i8];
      a1[i8] += e1; a2[i8] += e2;
      bool adjb = (fl & 1);
      if (adjb) aA[i8] += e1;
      if (!adjb && labn[i8] == labA && n != mcol){ aC[i8] += e1; aCc[i8] += 1.f; }
      if (n == mcol){ adI[i8] += e2; adi[i8] += e1; }
    }
    if (tile < 7){
      #pragma unroll
      for (int i = 0; i < 8; ++i) fA[i] = fB[i];
      labA = labB;
    }
  }
  #pragma unroll
  for (int i = 0; i < 8; ++i){
    #pragma unroll
    for (int o = 1; o < 16; o <<= 1){
      a1[i]  += __shfl_xor(a1[i], o);  a2[i]  += __shfl_xor(a2[i], o);
      aA[i]  += __shfl_xor(aA[i], o);  aC[i]  += __shfl_xor(aC[i], o);
      aCc[i] += __shfl_xor(aCc[i], o); adI[i] += __shfl_xor(adI[i], o);
      adi[i] += __shfl_xor(adi[i], o);
    }
  }
  if (l16 == 0){
    #pragma unroll
    for (int i = 0; i < 8; ++i){
      int n = nb + (i >> 2)*16 + lq*4 + (i & 3);
      atomicAdd(&rs1[n], a1[i]);  atomicAdd(&rs2[n], a2[i]);
      atomicAdd(&rsA[n], aA[i]);  atomicAdd(&rsC[n], aC[i]);
      atomicAdd(&rcC[n], aCc[i]); atomicAdd(&rdI[n], adI[i]);
      atomicAdd(&rdi[n], adi[i]);
    }
  }
}

// ---------------- contrastive loss finalize ----------------
__global__ __launch_bounds__(256) void k_clfinal(const float* __restrict__ rs1,
    const float* __restrict__ rs2, const float* __restrict__ rsA,
    const float* __restrict__ rsC, const float* __restrict__ rcC,
    const float* __restrict__ rdI, const float* __restrict__ rdi,
    const float* __restrict__ sadj, float* __restrict__ clsum)
{
  int n = blockIdx.x*256 + threadIdx.x;
  float pos = rdI[n] + rsA[n] + rsC[n];
  float den = rs1[n] + rs2[n] - rdi[n];
  float cnt = sadj[n] + rcC[n] + 1.f;
  float v = __logf(pos/den)/cnt;
  int lane = threadIdx.x & 63, wv = threadIdx.x >> 6;
  #pragma unroll
  for (int o = 32; o >= 1; o >>= 1) v += __shfl_xor(v, o);
  __shared__ float red[4];
  if (lane == 0) red[wv] = v;
  __syncthreads();
  if (threadIdx.x == 0) atomicAdd(clsum, red[0]+red[1]+red[2]+red[3]);
}

__global__ void k_loss(const float* __restrict__ scal, float* __restrict__ out){
  out[8192] = scal[0]*(1.f/4096.f) - scal[1];
}

// ---------------- output head (wave per row) ----------------
__global__ __launch_bounds__(256) void k_outhead(const float* __restrict__ z32,
    const float* __restrict__ pre_w, const float* __restrict__ pre_b,
    float* __restrict__ out)
{
  int lane = threadIdx.x & 63, wv = threadIdx.x >> 6;
  int n = blockIdx.x*4 + wv;
  float4 zv = *(const float4*)(z32 + ((size_t)n << 8) + lane*4);
  float4 w0 = *(const float4*)(pre_w + lane*8);
  float4 w1 = *(const float4*)(pre_w + lane*8 + 4);
  float c0 = zv.x*w0.x + zv.y*w0.z + zv.z*w1.x + zv.w*w1.z;
  float c1 = zv.x*w0.y + zv.y*w0.w + zv.z*w1.y + zv.w*w1.w;
  #pragma unroll
  for (int o = 32; o >= 1; o >>= 1){ c0 += __shfl_xor(c0, o); c1 += __shfl_xor(c1, o); }
  if (lane == 0){
    out[(size_t)n*2]     = c0 + pre_b[0];
    out[(size_t)n*2 + 1] = c1 + pre_b[1];
  }
}

// ---------------- host launch ----------------
extern "C" void kernel_launch(void* const* d_in, const int* in_sizes, int n_in,
                              void* d_out, int out_size, void* d_ws, size_t ws_size,
                              hipStream_t stream)
{
  const float* x         = (const float*)d_in[0];
  const float* x_demo    = (const float*)d_in[1];
  const int*   slen      = (const int*)d_in[2];
  const float* mask_edge = (const float*)d_in[3];
  const float* w_ih      = (const float*)d_in[4];
  const float* w_hh      = (const float*)d_in[5];
  const float* b_ih      = (const float*)d_in[6];
  const float* b_hh      = (const float*)d_in[7];
  const float* h0        = (const float*)d_in[8];
  const float* wq        = (const float*)d_in[9];
  const float* bq        = (const float*)d_in[10];
  const float* wk        = (const float*)d_in[11];
  const float* bk        = (const float*)d_in[12];
  const float* wo        = (const float*)d_in[13];
  const float* phi       = (const float*)d_in[15];
  const float* centers   = (const float*)d_in[16];
  const float* gcn_w     = (const float*)d_in[17];
  const float* gcn_b     = (const float*)d_in[18];
  const float* ffn_w     = (const float*)d_in[19];
  const float* ffn_b     = (const float*)d_in[20];
  const float* pre_w     = (const float*)d_in[21];
  const float* pre_b     = (const float*)d_in[22];
  float* out = (float*)d_out;

  size_t off = 0;
  char* base = (char*)d_ws;
  auto take = [&](size_t bytes)->void*{
    void* p = base + off;
    off += (bytes + 255) & ~(size_t)255;
    return p;
  };
  f16*   BgT    = (f16*)take((size_t)4*256*352*2);
  f16*   wq16   = (f16*)take((size_t)65536*2);
  f16*   wk16   = (f16*)take((size_t)65536*2);
  f16*   gw16   = (f16*)take((size_t)65536*2);
  float* biasc  = (float*)take(1008*4);
  int*   idx    = (int*)take(4096*4);
  float* xs32   = (float*)take((size_t)4096*256*4);
  f16*   xs16   = (f16*)take((size_t)4096*256*2);
  f16*   qf16   = (f16*)take((size_t)4096*256*2);
  f16*   kf16   = (f16*)take((size_t)4096*256*2);
  uint16_t* sco = (uint16_t*)take((size_t)4096*4096*2);
  uint8_t* flags= (uint8_t*)take((size_t)4096*4096);
  float* sadj   = (float*)take(4096*4);
  float* dinv   = (float*)take(4096*4);
  float* dinva  = (float*)take(4096*4);
  f16*   y16    = (f16*)take((size_t)4096*256*2);
  f16*   ya16   = (f16*)take((size_t)4096*256*2);
  float* z32    = (float*)take((size_t)4096*256*4);
  float* za32   = (float*)take((size_t)4096*256*4);
  f16*   zn16   = (f16*)take((size_t)4096*128*2);
  f16*   zan16  = (f16*)take((size_t)4096*128*2);
  float* qsoft  = (float*)take((size_t)4096*10*4);
  int*   labels = (int*)take(4096*4);
  float* colsum = (float*)take(64);
  float* scal   = (float*)take(64);         // [0]=klsum, [1]=clsum
  float* rsbuf  = (float*)take((size_t)7*4096*4);
  float* rs1 = rsbuf,        *rs2 = rsbuf + 4096, *rsA = rsbuf + 2*4096;
  float* rsC = rsbuf + 3*4096, *rcC = rsbuf + 4*4096;
  float* rdI = rsbuf + 5*4096, *rdi = rsbuf + 6*4096;

  // x16t[48][4096][96] fp16 (37.75 MB) aliases sco(33.55MB)+flags head:
  // x16t is only live during the GRU; sco/flags are written strictly after.
  f16* x16t = (f16*)sco;

  hipMemsetAsync(colsum, 0, 64, stream);
  hipMemsetAsync(scal, 0, 64, stream);
  hipMemsetAsync(rsbuf, 0, (size_t)7*4096*4, stream);

  k_prep<<<2196, 256, 0, stream>>>(w_ih, w_hh, b_ih, b_hh, slen, wq, wk, gcn_w,
                                   BgT, wq16, wk16, gw16, biasc, idx);
  k_xt<<<9216, 256, 0, stream>>>(x, x16t);
  k_xdemo<<<64, 256, 0, stream>>>(x_demo, xs32, xs16);
  k_gru_all<<<128, 1024, 0, stream>>>(x16t, BgT, biasc, h0, idx, xs32, xs16);
  k_projqk<<<dim3(64, 8), 256, 0, stream>>>(xs16, wq16, wk16, bq, bk, wo, qf16, kf16);
  k_scores<<<dim3(32, 32), 256, 0, stream>>>(qf16, kf16, sco);
  k_adj<<<4096, 256, 0, stream>>>(sco, mask_edge, phi, flags, sadj, dinv, dinva);
  k_xw_y<<<dim3(64, 4), 256, 0, stream>>>(xs16, gw16, dinv, dinva, y16, ya16);
  k_zgather<<<4096, 256, 0, stream>>>(flags, y16, ya16, dinv, dinva, gcn_b, z32, za32);
  k_cluster<<<256, 256, 0, stream>>>(xs32, centers, qsoft, labels, colsum);
  k_kl<<<16, 256, 0, stream>>>(qsoft, colsum, &scal[0]);
  k_ffn<<<dim3(4096, 2), 128, 0, stream>>>(z32, za32, ffn_w, ffn_b, zn16, zan16);
  k_closs<<<dim3(128, 8), 256, 0, stream>>>(zn16, zan16, flags, labels,
                                            rs1, rs2, rsA, rsC, rcC, rdI, rdi);
  k_clfinal<<<16, 256, 0, stream>>>(rs1, rs2, rsA, rsC, rcC, rdI, rdi, sadj, &scal[1]);
  k_loss<<<1, 1, 0, stream>>>(scal, out);
  k_outhead<<<1024, 256, 0, stream>>>(z32, pre_w, pre_b, out);

  (void)in_sizes; (void)n_in; (void)out_size; (void)ws_size;
}